// Round 9
// baseline (295.936 us; speedup 1.0000x reference)
//
#include <hip/hip_runtime.h>
#include <hip/hip_bf16.h>
#include <math.h>

#define B_ 8
#define S_ 192
#define D_ 512
#define L_ 8
#define SQ 1536   // S_*L_
#define H_ 2048
#define NROW (B_*SQ)   // 12288
#define SCALE_QK 0.04419417382415922f   // 1/sqrt(512)
#define SCALE_QK2 0.06377551974755906f  // SCALE_QK * log2(e)

typedef unsigned short ushort_t;
typedef unsigned int uint_t;
typedef __attribute__((ext_vector_type(8))) short bf16x8;
typedef __attribute__((ext_vector_type(4))) float f32x4;

__device__ __forceinline__ float bfu2f(ushort_t u) { return __uint_as_float((unsigned)u << 16); }
__device__ __forceinline__ ushort_t f2bfu(float f) {
  __hip_bfloat16 h = __float2bfloat16(f);
  return *reinterpret_cast<ushort_t*>(&h);
}

// tanh-form GELU: 0.5x(1+tanh(0.79788456(x+0.044715x^3))), max |err| ~3e-4.
__device__ __forceinline__ float gelu_tanh(float x) {
  float x2 = x * x;
  float u2 = x * fmaf(0.0713548162f, x2, 1.5957691216f);
  float e = __expf(u2);                       // e^(2u)
  float r = fmaf(-2.0f, __builtin_amdgcn_rcpf(e + 1.0f), 1.0f);  // tanh(u)
  float hx = 0.5f * x;
  return fmaf(hx, r, hx);
}

// async global->LDS, 16B per lane; LDS dest = wave-uniform base + lane*16
__device__ __forceinline__ void gl_lds16(const ushort_t* g, ushort_t* l) {
  __builtin_amdgcn_global_load_lds(
      (const __attribute__((address_space(1))) unsigned int*)g,
      (__attribute__((address_space(3))) unsigned int*)l, 16, 0, 0);
}

// counted vmcnt wait: leaves N newest VMEM ops in flight (T4).
#define VMWAIT(N) asm volatile("s_waitcnt vmcnt(" #N ")" ::: "memory")

// ---- fast build x: one block per (b,si); coalesced read of 4096 floats, LDS transpose.
// Emits x (f32), x_bf (bf16), xT_bf ([B][D][SQ]); also zeroes this block's 8
// rowsum entries (rows blockIdx.x*8..+7) -- replaces a separate k_zero dispatch.
__global__ __launch_bounds__(256) void k_build_x_f(const float* __restrict__ lags,
                                                   float* __restrict__ x,
                                                   ushort_t* __restrict__ x_bf,
                                                   ushort_t* __restrict__ xT,
                                                   float* __restrict__ rowsum) {
  __shared__ float tile[512][9];
  const int tid = threadIdx.x;
  if (tid < 8) rowsum[(size_t)blockIdx.x * 8 + tid] = 0.f;
  const float* in = lags + (size_t)blockIdx.x * 4096;
  #pragma unroll
  for (int it = 0; it < 4; ++it) {
    int f = (tid + it * 256) * 4;
    float4 v = *reinterpret_cast<const float4*>(in + f);
    int k = f >> 3, l0 = f & 7;
    tile[k][l0] = v.x; tile[k][l0 + 1] = v.y; tile[k][l0 + 2] = v.z; tile[k][l0 + 3] = v.w;
  }
  __syncthreads();
  const int l = tid >> 5, kbase = tid & 31;
  const size_t r = (size_t)blockIdx.x * 8 + l;
  #pragma unroll
  for (int j = 0; j < 16; ++j) {
    int k = kbase + 32 * j;
    float v = tile[k][l];
    x[r * D_ + k] = v;
    x_bf[r * D_ + k] = f2bfu(v);
  }
  const int b = blockIdx.x / S_, si = blockIdx.x - b * S_;
  #pragma unroll
  for (int dd = 0; dd < 2; ++dd) {
    int d = tid + dd * 256;
    uint_t pk[4];
    #pragma unroll
    for (int j = 0; j < 4; ++j) {
      uint_t lo = f2bfu(tile[d][2 * j]);
      uint_t hi = f2bfu(tile[d][2 * j + 1]);
      pk[j] = (hi << 16) | lo;
    }
    uint_t* dst = (uint_t*)(xT + ((size_t)b * D_ + d) * SQ + si * 8);
    *reinterpret_cast<uint4*>(dst) = make_uint4(pk[0], pk[1], pk[2], pk[3]);
  }
}

// ---- cast + transpose BOTH weights in one dispatch: W[K][N] fp32 -> Wt[N][K] bf16.
// blocks 0..255: W1 (K=512,N=2048, 32 n-blk x 8 k-blk); 256..511: W2 (K=2048,N=512).
__global__ __launch_bounds__(256) void k_wt2(const float* __restrict__ W1,
                                             ushort_t* __restrict__ w1t,
                                             const float* __restrict__ W2,
                                             ushort_t* __restrict__ w2t) {
  __shared__ ushort_t tile[64][65];
  int id = blockIdx.x;
  const float* W; ushort_t* Wt; int K, N, n0, k0;
  if (id < 256) {
    W = W1; Wt = w1t; K = D_; N = H_;
    n0 = (id & 31) * 64; k0 = (id >> 5) * 64;
  } else {
    id -= 256;
    W = W2; Wt = w2t; K = H_; N = D_;
    n0 = (id & 7) * 64; k0 = (id >> 3) * 64;
  }
  for (int i = threadIdx.x; i < 4096; i += 256) {
    int kk = i >> 6, nn = i & 63;
    tile[nn][kk] = f2bfu(W[(size_t)(k0 + kk) * N + n0 + nn]);
  }
  __syncthreads();
  for (int i = threadIdx.x; i < 4096; i += 256) {
    int nn = i >> 6, kk = i & 63;
    Wt[(size_t)(n0 + nn) * K + k0 + kk] = tile[nn][kk];
  }
}

// ---- bf16 MFMA GEMM (r3 core: 128x128 tile, 4 waves, BK=64, 2-buffer
// counted-vmcnt pipeline, zero-conflict swizzled LDS):  C = A[M,K] @ Bt[N,K]^T
// MODE 0: +bias, gelu -> bf16      | 1: +bias -> f32
// MODE 5: v * rcp(rsums[row]) -> f32   (softmax normalization folded in)
// MODE 6: SYMMETRIC exp-scores (A==Bt): triangular grid blockIdx.x in [0,78)
//         decodes (bi<=bj); stores bf16 exp(scale*v) at [bi,bj] AND mirrored
//         [bj,bi]; row sums via l15-reduce + atomicAdd, mirror row sums via
//         quad-reduce column sums + atomicAdd. Every (row,col) counted once.
// bias: MODE<=1 only. rsums: MODE 6 written / MODE 5 read; batch stride SQ.
template<int MODE>
__global__ __launch_bounds__(256) void k_gemm(const ushort_t* __restrict__ A,
                                              const ushort_t* __restrict__ Bt,
                                              const float* __restrict__ bias,
                                              float* __restrict__ rsums,
                                              void* __restrict__ Cout,
                                              int M, int K, int N,
                                              size_t sAz, size_t sBz, size_t sCz,
                                              float scale) {
  A  += (size_t)blockIdx.z * sAz;
  Bt += (size_t)blockIdx.z * sBz;
  __shared__ ushort_t As0[128 * 64];   // 16 KB each, 64 KB total -> 2 blocks/CU
  __shared__ ushort_t As1[128 * 64];
  __shared__ ushort_t Bs0[128 * 64];
  __shared__ ushort_t Bs1[128 * 64];
  const int tid = threadIdx.x;
  int m0, n0;
  if (MODE == 6) {
    int lidx = blockIdx.x, bi = 0;
    while (lidx >= 12 - bi) { lidx -= 12 - bi; ++bi; }   // 12 = SQ/128 panels
    m0 = bi * 128; n0 = (bi + lidx) * 128;               // bi <= bj
  } else {
    m0 = blockIdx.y * 128; n0 = blockIdx.x * 128;
  }
  const int w = tid >> 6, lane = tid & 63;
  const int wr = w >> 1, wc = w & 1;
  const int l15 = lane & 15, quad = lane >> 4;
  const int lrow8 = lane >> 3;                    // 0..7: staging row within 8-row group
  const int cg = ((lane & 7) ^ lrow8) * 8;        // swizzled global source chunk (ushorts)
  const int xsw = l15 & 7;                        // fragment-read xor
  const int lbase = (w * 32) * 64;                // wave-uniform LDS base offset
  const size_t sK8 = (size_t)8 * K;

  f32x4 acc[4][4];
  if (MODE <= 1) {
    #pragma unroll
    for (int nj = 0; nj < 4; ++nj) {
      float bv = bias[n0 + wc * 64 + nj * 16 + l15];
      #pragma unroll
      for (int mi = 0; mi < 4; ++mi) acc[mi][nj] = (f32x4){bv, bv, bv, bv};
    }
  } else {
    #pragma unroll
    for (int nj = 0; nj < 4; ++nj)
      #pragma unroll
      for (int mi = 0; mi < 4; ++mi) acc[mi][nj] = (f32x4){0.f, 0.f, 0.f, 0.f};
  }

  // per-thread staging source pointers; advance by 64 ushorts per staged tile
  const ushort_t* gA = A  + (size_t)(m0 + w * 32 + lrow8) * K + cg;
  const ushort_t* gB = Bt + (size_t)(n0 + w * 32 + lrow8) * K + cg;

#define STAGE(AS, BS) do {                                                  \
    ushort_t* la_ = &AS[lbase]; ushort_t* lb_ = &BS[lbase];                 \
    _Pragma("unroll")                                                       \
    for (int j_ = 0; j_ < 4; ++j_) {                                        \
      gl_lds16(gA + (size_t)j_ * sK8, la_ + j_ * 8 * 64);                   \
      gl_lds16(gB + (size_t)j_ * sK8, lb_ + j_ * 8 * 64);                   \
    }                                                                       \
    gA += 64; gB += 64;                                                     \
  } while (0)

#define COMPUTE(AS, BS) do {                                                \
    _Pragma("unroll")                                                       \
    for (int kk_ = 0; kk_ < 2; ++kk_) {                                     \
      const int csel_ = ((kk_ * 4 + quad) ^ xsw) * 8;                       \
      bf16x8 af_[4], bf_[4];                                                \
      _Pragma("unroll")                                                     \
      for (int mi_ = 0; mi_ < 4; ++mi_)                                     \
        af_[mi_] = *reinterpret_cast<const bf16x8*>(                        \
            &AS[(wr * 64 + mi_ * 16 + l15) * 64 + csel_]);                  \
      _Pragma("unroll")                                                     \
      for (int nj_ = 0; nj_ < 4; ++nj_)                                     \
        bf_[nj_] = *reinterpret_cast<const bf16x8*>(                        \
            &BS[(wc * 64 + nj_ * 16 + l15) * 64 + csel_]);                  \
      _Pragma("unroll")                                                     \
      for (int mi_ = 0; mi_ < 4; ++mi_)                                     \
        _Pragma("unroll")                                                   \
        for (int nj_ = 0; nj_ < 4; ++nj_)                                   \
          acc[mi_][nj_] = __builtin_amdgcn_mfma_f32_16x16x32_bf16(          \
              af_[mi_], bf_[nj_], acc[mi_][nj_], 0, 0, 0);                  \
    }                                                                       \
  } while (0)

  // prologue: stage tiles 0 and 1 (16 loads/wave in flight)
  STAGE(As0, Bs0);
  STAGE(As1, Bs1);

  const int nt = K >> 6;   // even, >= 8 for all call sites
  for (int t = 0; t < nt - 2; t += 2) {
    VMWAIT(8);                        // tile t landed; tile t+1 stays in flight
    __builtin_amdgcn_s_barrier();
    COMPUTE(As0, Bs0);                // compute tile t
    __builtin_amdgcn_s_barrier();     // join: all waves done reading buf0
    STAGE(As0, Bs0);                  // prefetch tile t+2
    VMWAIT(8);                        // tile t+1 landed; tile t+2 in flight
    __builtin_amdgcn_s_barrier();
    COMPUTE(As1, Bs1);                // compute tile t+1
    __builtin_amdgcn_s_barrier();     // join: all waves done reading buf1
    STAGE(As1, Bs1);                  // prefetch tile t+3
  }
  // tail: tiles nt-2 (buf0) and nt-1 (buf1) staged, nothing more to prefetch
  VMWAIT(8);
  __builtin_amdgcn_s_barrier();
  COMPUTE(As0, Bs0);
  VMWAIT(0);
  __builtin_amdgcn_s_barrier();
  COMPUTE(As1, Bs1);

#undef STAGE
#undef COMPUTE

  ushort_t* Cb = (ushort_t*)Cout + (size_t)blockIdx.z * sCz;
  float*    Cf = (float*)Cout    + (size_t)blockIdx.z * sCz;

  if (MODE == 6) {
    // symmetric exp-scores epilogue.
    float* rs = rsums + (size_t)blockIdx.z * SQ;
    const bool offdiag = (m0 != n0);
    float colpart[4] = {0.f, 0.f, 0.f, 0.f};   // per-nj partial column sums
    #pragma unroll
    for (int mi = 0; mi < 4; ++mi)
      #pragma unroll
      for (int r = 0; r < 4; ++r) {
        int gr = m0 + wr * 64 + mi * 16 + quad * 4 + r;
        float s = 0.f;
        #pragma unroll
        for (int nj = 0; nj < 4; ++nj) {
          int gc = n0 + wc * 64 + nj * 16 + l15;
          float e = exp2f(acc[mi][nj][r] * scale);   // scale includes log2(e)
          ushort_t ub = f2bfu(e);
          Cb[(size_t)gr * N + gc] = ub;
          if (offdiag) Cb[(size_t)gc * N + gr] = ub; // mirrored tile (L2 merges)
          float er = bfu2f(ub);                      // sum the ROUNDED values
          s += er;
          colpart[nj] += er;
        }
        #pragma unroll
        for (int m_ = 1; m_ < 16; m_ <<= 1) s += __shfl_xor(s, m_);
        if (l15 == 0) atomicAdd(&rs[gr], s);
      }
    if (offdiag) {
      #pragma unroll
      for (int nj = 0; nj < 4; ++nj) {
        float cs = colpart[nj];
        cs += __shfl_xor(cs, 16);                    // reduce over quad lanes
        cs += __shfl_xor(cs, 32);
        if (quad == 0) atomicAdd(&rs[n0 + wc * 64 + nj * 16 + l15], cs);
      }
    }
  } else {
    const float* rsr = rsums + (size_t)blockIdx.z * SQ;  // MODE 5 only
    #pragma unroll
    for (int mi = 0; mi < 4; ++mi)
      #pragma unroll
      for (int nj = 0; nj < 4; ++nj) {
        int gc = n0 + wc * 64 + nj * 16 + l15;
        #pragma unroll
        for (int r = 0; r < 4; ++r) {
          int gr = m0 + wr * 64 + mi * 16 + quad * 4 + r;
          float v = acc[mi][nj][r];
          if (MODE == 0) {
            Cb[(size_t)gr * N + gc] = f2bfu(gelu_tanh(v));
          } else if (MODE == 1) {
            Cf[(size_t)gr * N + gc] = v;
          } else if (MODE == 5) {
            Cf[(size_t)gr * N + gc] = v * __builtin_amdgcn_rcpf(rsr[gr]);
          } else {
            Cf[(size_t)gr * N + gc] = v;
          }
        }
      }
  }
}

// ---- LN1 -> bf16 q ----
__global__ __launch_bounds__(256) void k_ln1b(const float* __restrict__ x,
                                              const float* __restrict__ attn,
                                              const float* __restrict__ g,
                                              const float* __restrict__ be,
                                              ushort_t* __restrict__ qbf) {
  size_t base = (size_t)blockIdx.x * D_;
  int tid = threadIdx.x;
  __shared__ float rl[8];
  float v0 = x[base + tid] + attn[base + tid];
  float v1 = x[base + tid + 256] + attn[base + tid + 256];
  float s = v0 + v1, sq = v0 * v0 + v1 * v1;
  #pragma unroll
  for (int o = 32; o > 0; o >>= 1) { s += __shfl_down(s, o); sq += __shfl_down(sq, o); }
  int lane = tid & 63, wid = tid >> 6;
  if (lane == 0) { rl[wid] = s; rl[4 + wid] = sq; }
  __syncthreads();
  s = rl[0] + rl[1] + rl[2] + rl[3];
  sq = rl[4] + rl[5] + rl[6] + rl[7];
  float mean = s * (1.0f / 512.0f);
  float var = sq * (1.0f / 512.0f) - mean * mean;
  float rstd = rsqrtf(var + 1e-5f);
  qbf[base + tid]       = f2bfu((v0 - mean) * rstd * g[tid] + be[tid]);
  qbf[base + tid + 256] = f2bfu((v1 - mean) * rstd * g[tid + 256] + be[tid + 256]);
}

// ---- fast LN3: one block per (b,si); LDS transpose -> fully coalesced output ----
__global__ __launch_bounds__(256) void k_ln3_f(const float* __restrict__ y,
                                               const ushort_t* __restrict__ qbf,
                                               const float* __restrict__ g3,
                                               const float* __restrict__ be3,
                                               float* __restrict__ out) {
  __shared__ float ynorm[8][512];
  const int tid = threadIdx.x;
  const int w = tid >> 6, lane = tid & 63;
  #pragma unroll
  for (int rr = 0; rr < 2; ++rr) {
    int l = 2 * w + rr;
    size_t t = (size_t)blockIdx.x * 8 + l;
    float v[8];
    float s = 0.f, sq = 0.f;
    #pragma unroll
    for (int j = 0; j < 8; ++j) {
      int k = lane + 64 * j;
      v[j] = y[t * D_ + k] + bfu2f(qbf[t * D_ + k]);
      s += v[j]; sq += v[j] * v[j];
    }
    #pragma unroll
    for (int o = 32; o > 0; o >>= 1) { s += __shfl_down(s, o); sq += __shfl_down(sq, o); }
    s = __shfl(s, 0); sq = __shfl(sq, 0);
    float mean = s * (1.0f / 512.0f);
    float var = sq * (1.0f / 512.0f) - mean * mean;
    float rstd = rsqrtf(var + 1e-5f);
    #pragma unroll
    for (int j = 0; j < 8; ++j) {
      int k = lane + 64 * j;
      ynorm[l][k] = (v[j] - mean) * rstd * g3[k] + be3[k];
    }
  }
  __syncthreads();
  float* ob = out + (size_t)blockIdx.x * 4096;
  #pragma unroll
  for (int kk = 0; kk < 2; ++kk) {
    int k = tid * 2 + kk;
    float4 lo = make_float4(ynorm[0][k], ynorm[1][k], ynorm[2][k], ynorm[3][k]);
    float4 hi = make_float4(ynorm[4][k], ynorm[5][k], ynorm[6][k], ynorm[7][k]);
    *reinterpret_cast<float4*>(ob + (size_t)k * 8)     = lo;
    *reinterpret_cast<float4*>(ob + (size_t)k * 8 + 4) = hi;
  }
}

// ================= slow-path fp32 kernels (fallback only) =================
#define TS 64
#define KT 16
__global__ __launch_bounds__(256) void k_build_x_s(const float* __restrict__ lags,
                                                   float* __restrict__ x, int b_base) {
  int idx = blockIdx.x * 256 + threadIdx.x;
  int k = idx & (D_ - 1);
  int r = idx >> 9;
  int b = b_base + r / SQ;
  int t = r - (r / SQ) * SQ;
  int si = t >> 3, l = t & 7;
  size_t src = (((size_t)(b * S_ + si) * D_ + k) << 3) + l;
  x[idx] = lags[src];
}

__global__ __launch_bounds__(256) void k_scores(const float* __restrict__ x,
                                                float* __restrict__ sc, int b_base) {
  const float* A = x;
  float* C = sc;
  __shared__ float As[TS][KT + 1];
  __shared__ float Bs[TS][KT + 1];
  int tx = threadIdx.x & 15, ty = threadIdx.x >> 4;
  int j0 = blockIdx.x * TS, i0 = blockIdx.y * TS;
  float acc[4][4] = {};
  int lk = threadIdx.x & 15, lr = threadIdx.x >> 4;
  for (int k0 = 0; k0 < D_; k0 += KT) {
    #pragma unroll
    for (int it = 0; it < 4; ++it) {
      As[lr + 16 * it][lk] = A[(size_t)(i0 + lr + 16 * it) * D_ + k0 + lk];
      Bs[lr + 16 * it][lk] = A[(size_t)(j0 + lr + 16 * it) * D_ + k0 + lk];
    }
    __syncthreads();
    #pragma unroll
    for (int kk = 0; kk < KT; ++kk) {
      float a[4], bb[4];
      #pragma unroll
      for (int r = 0; r < 4; ++r) a[r] = As[ty * 4 + r][kk];
      #pragma unroll
      for (int c = 0; c < 4; ++c) bb[c] = Bs[tx * 4 + c][kk];
      #pragma unroll
      for (int r = 0; r < 4; ++r)
        #pragma unroll
        for (int c = 0; c < 4; ++c) acc[r][c] = fmaf(a[r], bb[c], acc[r][c]);
    }
    __syncthreads();
  }
  #pragma unroll
  for (int r = 0; r < 4; ++r) {
    float4 v = make_float4(acc[r][0]*SCALE_QK, acc[r][1]*SCALE_QK,
                           acc[r][2]*SCALE_QK, acc[r][3]*SCALE_QK);
    *reinterpret_cast<float4*>(&C[(size_t)(i0 + ty*4 + r) * SQ + j0 + tx*4]) = v;
  }
}

__global__ __launch_bounds__(256) void k_softmax(float* __restrict__ sc) {
  float* row = sc + (size_t)blockIdx.x * SQ;
  int tid = threadIdx.x;
  __shared__ float red[8];
  float m = -1e30f;
  for (int j = tid; j < SQ; j += 256) m = fmaxf(m, row[j]);
  #pragma unroll
  for (int o = 32; o > 0; o >>= 1) m = fmaxf(m, __shfl_down(m, o));
  if ((tid & 63) == 0) red[tid >> 6] = m;
  __syncthreads();
  m = fmaxf(fmaxf(red[0], red[1]), fmaxf(red[2], red[3]));
  __syncthreads();
  float ssum = 0.f;
  for (int j = tid; j < SQ; j += 256) { float e = expf(row[j] - m); row[j] = e; ssum += e; }
  #pragma unroll
  for (int o = 32; o > 0; o >>= 1) ssum += __shfl_down(ssum, o);
  if ((tid & 63) == 0) red[4 + (tid >> 6)] = ssum;
  __syncthreads();
  float inv = 1.0f / (red[4] + red[5] + red[6] + red[7]);
  for (int j = tid; j < SQ; j += 256) row[j] *= inv;
}

__global__ __launch_bounds__(256) void k_attn(const float* __restrict__ x,
                                              const float* __restrict__ sc,
                                              float* __restrict__ attn) {
  const float* X = x;
  const float* P = sc;
  float* O = attn;
  __shared__ float Ps[TS][KT + 1];
  __shared__ float Xs[KT][TS];
  int tx = threadIdx.x & 15, ty = threadIdx.x >> 4;
  int j0 = blockIdx.x * TS, i0 = blockIdx.y * TS;
  float acc[4][4] = {};
  int lk = threadIdx.x & 15, lr = threadIdx.x >> 4;
  int lc = threadIdx.x & 63, lrow = threadIdx.x >> 6;
  for (int k0 = 0; k0 < SQ; k0 += KT) {
    #pragma unroll
    for (int it = 0; it < 4; ++it)
      Ps[lr + 16 * it][lk] = P[(size_t)(i0 + lr + 16 * it) * SQ + k0 + lk];
    #pragma unroll
    for (int it = 0; it < 4; ++it)
      Xs[lrow + 4 * it][lc] = X[(size_t)(k0 + lrow + 4 * it) * D_ + j0 + lc];
    __syncthreads();
    #pragma unroll
    for (int kk = 0; kk < KT; ++kk) {
      float a[4], bb[4];
      #pragma unroll
      for (int r = 0; r < 4; ++r) a[r] = Ps[ty * 4 + r][kk];
      #pragma unroll
      for (int c = 0; c < 4; ++c) bb[c] = Xs[kk][tx * 4 + c];
      #pragma unroll
      for (int r = 0; r < 4; ++r)
        #pragma unroll
        for (int c = 0; c < 4; ++c) acc[r][c] = fmaf(a[r], bb[c], acc[r][c]);
    }
    __syncthreads();
  }
  #pragma unroll
  for (int r = 0; r < 4; ++r) {
    float4 v = make_float4(acc[r][0], acc[r][1], acc[r][2], acc[r][3]);
    *reinterpret_cast<float4*>(&O[(size_t)(i0 + ty*4 + r) * D_ + j0 + tx*4]) = v;
  }
}

__global__ __launch_bounds__(256) void k_ln1(const float* __restrict__ x,
                                             const float* __restrict__ attn,
                                             const float* __restrict__ g,
                                             const float* __restrict__ be,
                                             float* __restrict__ qout) {
  size_t base = (size_t)blockIdx.x * D_;
  int tid = threadIdx.x;
  __shared__ float rl[8];
  float v0 = x[base + tid] + attn[base + tid];
  float v1 = x[base + tid + 256] + attn[base + tid + 256];
  float s = v0 + v1, sq = v0 * v0 + v1 * v1;
  #pragma unroll
  for (int o = 32; o > 0; o >>= 1) { s += __shfl_down(s, o); sq += __shfl_down(sq, o); }
  int lane = tid & 63, wid = tid >> 6;
  if (lane == 0) { rl[wid] = s; rl[4 + wid] = sq; }
  __syncthreads();
  s = rl[0] + rl[1] + rl[2] + rl[3];
  sq = rl[4] + rl[5] + rl[6] + rl[7];
  float mean = s * (1.0f / 512.0f);
  float var = sq * (1.0f / 512.0f) - mean * mean;
  float rstd = rsqrtf(var + 1e-5f);
  qout[base + tid]       = (v0 - mean) * rstd * g[tid] + be[tid];
  qout[base + tid + 256] = (v1 - mean) * rstd * g[tid + 256] + be[tid + 256];
}

__global__ __launch_bounds__(256, 2) void k_ffn(
    const float* __restrict__ q,
    const float* __restrict__ W1, const float* __restrict__ b1,
    const float* __restrict__ W2, const float* __restrict__ b2,
    const float* __restrict__ g3, const float* __restrict__ be3,
    float* __restrict__ out, int row_base)
{
  __shared__ float qs[8][D_];
  __shared__ float mid[8][H_];
  const int tid = threadIdx.x;
  const int row0 = blockIdx.x * 8;
  for (int idx = tid; idx < 8 * D_; idx += 256)
    qs[idx >> 9][idx & (D_ - 1)] = q[(size_t)row0 * D_ + idx];
  __syncthreads();
  float acc[8][8];
  {
    float4 bA = *reinterpret_cast<const float4*>(b1 + (tid << 3));
    float4 bB = *reinterpret_cast<const float4*>(b1 + (tid << 3) + 4);
    float bv[8] = {bA.x, bA.y, bA.z, bA.w, bB.x, bB.y, bB.z, bB.w};
    #pragma unroll
    for (int jj = 0; jj < 8; ++jj)
      #pragma unroll
      for (int r = 0; r < 8; ++r) acc[jj][r] = bv[jj];
  }
  for (int k4 = 0; k4 < D_ / 4; ++k4) {
    float4 qv[8];
    #pragma unroll
    for (int r = 0; r < 8; ++r)
      qv[r] = *reinterpret_cast<const float4*>(&qs[r][k4 << 2]);
    #pragma unroll
    for (int kk = 0; kk < 4; ++kk) {
      const int k = (k4 << 2) + kk;
      float4 wA = *reinterpret_cast<const float4*>(W1 + (size_t)k * H_ + (tid << 3));
      float4 wB = *reinterpret_cast<const float4*>(W1 + (size_t)k * H_ + (tid << 3) + 4);
      float wv[8] = {wA.x, wA.y, wA.z, wA.w, wB.x, wB.y, wB.z, wB.w};
      #pragma unroll
      for (int r = 0; r < 8; ++r) {
        float qk = (kk == 0) ? qv[r].x : (kk == 1) ? qv[r].y : (kk == 2) ? qv[r].z : qv[r].w;
        #pragma unroll
        for (int jj = 0; jj < 8; ++jj) acc[jj][r] = fmaf(qk, wv[jj], acc[jj][r]);
      }
    }
  }
  #pragma unroll
  for (int jj = 0; jj < 8; ++jj)
    #pragma unroll
    for (int r = 0; r < 8; ++r) {
      float v = acc[jj][r];
      mid[r][(tid << 3) + jj] = 0.5f * v * (1.0f + erff(v * 0.70710678118654752f));
    }
  __syncthreads();
  float acc2[8][2];
  {
    float b20 = b2[tid << 1], b21 = b2[(tid << 1) + 1];
    #pragma unroll
    for (int r = 0; r < 8; ++r) { acc2[r][0] = b20; acc2[r][1] = b21; }
  }
  for (int j4 = 0; j4 < H_ / 4; ++j4) {
    float4 mv[8];
    #pragma unroll
    for (int r = 0; r < 8; ++r)
      mv[r] = *reinterpret_cast<const float4*>(&mid[r][j4 << 2]);
    #pragma unroll
    for (int kk = 0; kk < 4; ++kk) {
      const int j = (j4 << 2) + kk;
      float2 wv = *reinterpret_cast<const float2*>(W2 + (size_t)j * D_ + (tid << 1));
      #pragma unroll
      for (int r = 0; r < 8; ++r) {
        float m = (kk == 0) ? mv[r].x : (kk == 1) ? mv[r].y : (kk == 2) ? mv[r].z : mv[r].w;
        acc2[r][0] = fmaf(m, wv.x, acc2[r][0]);
        acc2[r][1] = fmaf(m, wv.y, acc2[r][1]);
      }
    }
  }
  __syncthreads();
  float* ys = &mid[0][0];
  #pragma unroll
  for (int r = 0; r < 8; ++r) {
    ys[r * D_ + (tid << 1)]     = qs[r][(tid << 1)]     + acc2[r][0];
    ys[r * D_ + (tid << 1) + 1] = qs[r][(tid << 1) + 1] + acc2[r][1];
  }
  __syncthreads();
  float g3a = g3[tid],  g3b = g3[tid + 256];
  float be3a = be3[tid], be3b = be3[tid + 256];
  float* rl = &qs[0][0];
  for (int r = 0; r < 8; ++r) {
    float v0 = ys[r * D_ + tid], v1 = ys[r * D_ + tid + 256];
    float s = v0 + v1, sq = v0 * v0 + v1 * v1;
    #pragma unroll
    for (int o = 32; o > 0; o >>= 1) { s += __shfl_down(s, o); sq += __shfl_down(sq, o); }
    int lane = tid & 63, wid = tid >> 6;
    if (lane == 0) { rl[wid] = s; rl[4 + wid] = sq; }
    __syncthreads();
    s = rl[0] + rl[1] + rl[2] + rl[3];
    sq = rl[4] + rl[5] + rl[6] + rl[7];
    __syncthreads();
    float mean = s * (1.0f / 512.0f);
    float var = sq * (1.0f / 512.0f) - mean * mean;
    float rstd = rsqrtf(var + 1e-5f);
    int t = row_base + row0 + r;
    int b = t / SQ, tt = t - b * SQ;
    int si = tt >> 3, l = tt & 7;
    size_t ob = (((size_t)(b * S_ + si) * D_) << 3) + l;
    out[ob + ((size_t)tid << 3)]         = (v0 - mean) * rstd * g3a + be3a;
    out[ob + ((size_t)(tid + 256) << 3)] = (v1 - mean) * rstd * g3b + be3b;
  }
}

extern "C" void kernel_launch(void* const* d_in, const int* in_sizes, int n_in,
                              void* d_out, int out_size, void* d_ws, size_t ws_size,
                              hipStream_t stream) {
  const float* lags   = (const float*)d_in[0];
  const float* gamma1 = (const float*)d_in[1];
  const float* beta1  = (const float*)d_in[2];
  const float* W1     = (const float*)d_in[3];
  const float* b1     = (const float*)d_in[4];
  const float* W2     = (const float*)d_in[5];
  const float* b2     = (const float*)d_in[6];
  const float* g3     = (const float*)d_in[7];
  const float* be3    = (const float*)d_in[8];
  float* out = (float*)d_out;

  float* ws = (float*)d_ws;
  const size_t NX  = (size_t)B_ * SQ * D_;   // 6,291,456
  const size_t NXB = (size_t)SQ * D_;        //   786,432
  const size_t NS  = (size_t)SQ * SQ;        // 2,359,296

  const size_t need_full = (3 * NX + 8 * NS) * sizeof(float);  // ~151 MB (proven available)

  if (ws_size >= need_full) {
    // ---- fast path layout (~130 MB) ----
    float* x        = ws;                                   // NX f32
    float* attn     = x + NX;                               // NX f32 (later: y)
    ushort_t* q_bf  = (ushort_t*)(attn + NX);               // NX us
    ushort_t* w1t   = q_bf + NX;                            // H*D us
    ushort_t* w2t   = w1t + (size_t)H_ * D_;                // H*D us
    float* rowsum   = (float*)(w2t + (size_t)H_ * D_);      // B*SQ f32 (48 KB)
    ushort_t* region = (ushort_t*)(rowsum + (size_t)B_ * SQ); // 8*NS + 2*NX us
    ushort_t* sc_bf = region;                               // exp-scores, bf16
    ushort_t* x_bf  = region + 8 * NS;
    ushort_t* xT_bf = x_bf + NX;
    ushort_t* mid_bf = region;                              // aliases dead sc/x_bf/xT_bf

    k_build_x_f<<<dim3(B_ * S_), 256, 0, stream>>>(lags, x, x_bf, xT_bf, rowsum);
    k_wt2<<<dim3(512), 256, 0, stream>>>(W1, w1t, W2, w2t);
    // P = exp(scale * X X^T) -> bf16 (SYMMETRIC: 78 triangular blocks/batch,
    // off-diagonal tiles mirrored); rowsum accumulated (row + column sums).
    // No max-sub needed: scores <= ~31 -> exp <= 3e13, f32-safe.
    k_gemm<6><<<dim3(78, 1, B_), 256, 0, stream>>>(
        x_bf, x_bf, nullptr, rowsum, sc_bf, SQ, D_, SQ, NXB, NXB, NS, SCALE_QK2);
    // attn = (P @ X) / rowsum -> f32  (softmax normalization folded in)
    k_gemm<5><<<dim3(D_ / 128, SQ / 128, B_), 256, 0, stream>>>(
        sc_bf, xT_bf, nullptr, rowsum, attn, SQ, SQ, D_, NS, NXB, NXB, 1.0f);
    k_ln1b<<<dim3(NROW), 256, 0, stream>>>(x, attn, gamma1, beta1, q_bf);
    // mid = gelu(q @ W1 + b1) -> bf16
    k_gemm<0><<<dim3(H_ / 128, NROW / 128, 1), 256, 0, stream>>>(
        q_bf, w1t, b1, nullptr, mid_bf, NROW, D_, H_, 0, 0, 0, 1.0f);
    // y = mid @ W2 + b2 -> f32 (attn buffer)
    k_gemm<1><<<dim3(D_ / 128, NROW / 128, 1), 256, 0, stream>>>(
        mid_bf, w2t, b2, nullptr, attn, NROW, H_, D_, 0, 0, 0, 1.0f);
    k_ln3_f<<<dim3(B_ * S_), 256, 0, stream>>>(attn, q_bf, g3, be3, out);
  } else {
    // ---- minimal-footprint fallback (fp32, per-batch) ----
    float* xb   = ws;
    float* sc   = xb + NXB;
    float* atb  = sc + NS;
    float* qb   = atb + NXB;
    for (int b = 0; b < B_; ++b) {
      k_build_x_s<<<dim3((unsigned)(NXB / 256)), 256, 0, stream>>>(lags, xb, b);
      k_scores<<<dim3(SQ / TS, SQ / TS, 1), 256, 0, stream>>>(xb, sc, b);
      k_softmax<<<dim3(SQ, 1, 1), 256, 0, stream>>>(sc);
      k_attn<<<dim3(D_ / TS, SQ / TS, 1), 256, 0, stream>>>(xb, sc, atb);
      k_ln1<<<dim3(SQ), 256, 0, stream>>>(xb, atb, gamma1, beta1, qb);
      k_ffn<<<dim3(SQ / 8), 256, 0, stream>>>(qb, W1, b1, W2, b2, g3, be3, out, b * SQ);
    }
  }
}

// Round 10
// 284.451 us; speedup vs baseline: 1.0404x; 1.0404x over previous
//
#include <hip/hip_runtime.h>
#include <hip/hip_bf16.h>
#include <math.h>

#define B_ 8
#define S_ 192
#define D_ 512
#define L_ 8
#define SQ 1536   // S_*L_
#define H_ 2048
#define NROW (B_*SQ)   // 12288
#define SCALE_QK 0.04419417382415922f   // 1/sqrt(512)
#define SCALE_QK2 0.06377551974755906f  // SCALE_QK * log2(e)

typedef unsigned short ushort_t;
typedef unsigned int uint_t;
typedef __attribute__((ext_vector_type(8))) short bf16x8;
typedef __attribute__((ext_vector_type(4))) float f32x4;

__device__ __forceinline__ float bfu2f(ushort_t u) { return __uint_as_float((unsigned)u << 16); }
__device__ __forceinline__ ushort_t f2bfu(float f) {
  __hip_bfloat16 h = __float2bfloat16(f);
  return *reinterpret_cast<ushort_t*>(&h);
}

// tanh-form GELU: 0.5x(1+tanh(0.79788456(x+0.044715x^3))), max |err| ~3e-4.
__device__ __forceinline__ float gelu_tanh(float x) {
  float x2 = x * x;
  float u2 = x * fmaf(0.0713548162f, x2, 1.5957691216f);
  float e = __expf(u2);                       // e^(2u)
  float r = fmaf(-2.0f, __builtin_amdgcn_rcpf(e + 1.0f), 1.0f);  // tanh(u)
  float hx = 0.5f * x;
  return fmaf(hx, r, hx);
}

// async global->LDS, 16B per lane; LDS dest = wave-uniform base + lane*16
__device__ __forceinline__ void gl_lds16(const ushort_t* g, ushort_t* l) {
  __builtin_amdgcn_global_load_lds(
      (const __attribute__((address_space(1))) unsigned int*)g,
      (__attribute__((address_space(3))) unsigned int*)l, 16, 0, 0);
}

// counted vmcnt wait: leaves N newest VMEM ops in flight (T4).
#define VMWAIT(N) asm volatile("s_waitcnt vmcnt(" #N ")" ::: "memory")

// ---- fast build x: one block per (b,si); coalesced read of 4096 floats, LDS transpose.
// Emits x (f32), x_bf (bf16), xT_bf ([B][D][SQ]); also zeroes this block's 8
// rowsum entries (rows blockIdx.x*8..+7) -- replaces a separate k_zero dispatch.
__global__ __launch_bounds__(256) void k_build_x_f(const float* __restrict__ lags,
                                                   float* __restrict__ x,
                                                   ushort_t* __restrict__ x_bf,
                                                   ushort_t* __restrict__ xT,
                                                   float* __restrict__ rowsum) {
  __shared__ float tile[512][9];
  const int tid = threadIdx.x;
  if (tid < 8) rowsum[(size_t)blockIdx.x * 8 + tid] = 0.f;
  const float* in = lags + (size_t)blockIdx.x * 4096;
  #pragma unroll
  for (int it = 0; it < 4; ++it) {
    int f = (tid + it * 256) * 4;
    float4 v = *reinterpret_cast<const float4*>(in + f);
    int k = f >> 3, l0 = f & 7;
    tile[k][l0] = v.x; tile[k][l0 + 1] = v.y; tile[k][l0 + 2] = v.z; tile[k][l0 + 3] = v.w;
  }
  __syncthreads();
  const int l = tid >> 5, kbase = tid & 31;
  const size_t r = (size_t)blockIdx.x * 8 + l;
  #pragma unroll
  for (int j = 0; j < 16; ++j) {
    int k = kbase + 32 * j;
    float v = tile[k][l];
    x[r * D_ + k] = v;
    x_bf[r * D_ + k] = f2bfu(v);
  }
  const int b = blockIdx.x / S_, si = blockIdx.x - b * S_;
  #pragma unroll
  for (int dd = 0; dd < 2; ++dd) {
    int d = tid + dd * 256;
    uint_t pk[4];
    #pragma unroll
    for (int j = 0; j < 4; ++j) {
      uint_t lo = f2bfu(tile[d][2 * j]);
      uint_t hi = f2bfu(tile[d][2 * j + 1]);
      pk[j] = (hi << 16) | lo;
    }
    uint_t* dst = (uint_t*)(xT + ((size_t)b * D_ + d) * SQ + si * 8);
    *reinterpret_cast<uint4*>(dst) = make_uint4(pk[0], pk[1], pk[2], pk[3]);
  }
}

// ---- cast + transpose BOTH weights in one dispatch: W[K][N] fp32 -> Wt[N][K] bf16.
// blocks 0..255: W1 (K=512,N=2048, 32 n-blk x 8 k-blk); 256..511: W2 (K=2048,N=512).
__global__ __launch_bounds__(256) void k_wt2(const float* __restrict__ W1,
                                             ushort_t* __restrict__ w1t,
                                             const float* __restrict__ W2,
                                             ushort_t* __restrict__ w2t) {
  __shared__ ushort_t tile[64][65];
  int id = blockIdx.x;
  const float* W; ushort_t* Wt; int K, N, n0, k0;
  if (id < 256) {
    W = W1; Wt = w1t; K = D_; N = H_;
    n0 = (id & 31) * 64; k0 = (id >> 5) * 64;
  } else {
    id -= 256;
    W = W2; Wt = w2t; K = H_; N = D_;
    n0 = (id & 7) * 64; k0 = (id >> 3) * 64;
  }
  for (int i = threadIdx.x; i < 4096; i += 256) {
    int kk = i >> 6, nn = i & 63;
    tile[nn][kk] = f2bfu(W[(size_t)(k0 + kk) * N + n0 + nn]);
  }
  __syncthreads();
  for (int i = threadIdx.x; i < 4096; i += 256) {
    int nn = i >> 6, kk = i & 63;
    Wt[(size_t)(n0 + nn) * K + k0 + kk] = tile[nn][kk];
  }
}

// ---- bf16 MFMA GEMM (r3 core: 128x128 tile, 4 waves, BK=64, 2-buffer
// counted-vmcnt pipeline, zero-conflict swizzled LDS):  C = A[M,K] @ Bt[N,K]^T
// MODE 0: +bias, gelu -> bf16      | 1: +bias -> f32
// MODE 5: v * rcp(rsums[row]) -> f32   (softmax normalization folded in)
// MODE 6: SYMMETRIC exp-scores (A==Bt): triangular grid blockIdx.x in [0,78)
//         decodes (bi<=bj); stores bf16 exp(scale*v) at [bi,bj]; mirrored tile
//         [bj,bi] is staged in LDS (As0/Bs0, free after K-loop; XOR-swizzled)
//         and written COALESCED (fixes r9's 2B-scatter regression).
//         Row sums via l15-reduce + atomicAdd; mirror row sums via quad-reduce
//         column sums + atomicAdd. Every (row,col) counted exactly once.
// bias: MODE<=1 only. rsums: MODE 6 written / MODE 5 read; batch stride SQ.
template<int MODE>
__global__ __launch_bounds__(256) void k_gemm(const ushort_t* __restrict__ A,
                                              const ushort_t* __restrict__ Bt,
                                              const float* __restrict__ bias,
                                              float* __restrict__ rsums,
                                              void* __restrict__ Cout,
                                              int M, int K, int N,
                                              size_t sAz, size_t sBz, size_t sCz,
                                              float scale) {
  A  += (size_t)blockIdx.z * sAz;
  Bt += (size_t)blockIdx.z * sBz;
  __shared__ ushort_t As0[128 * 64];   // 16 KB each, 64 KB total -> 2 blocks/CU
  __shared__ ushort_t As1[128 * 64];
  __shared__ ushort_t Bs0[128 * 64];
  __shared__ ushort_t Bs1[128 * 64];
  const int tid = threadIdx.x;
  int m0, n0;
  if (MODE == 6) {
    int lidx = blockIdx.x, bi = 0;
    while (lidx >= 12 - bi) { lidx -= 12 - bi; ++bi; }   // 12 = SQ/128 panels
    m0 = bi * 128; n0 = (bi + lidx) * 128;               // bi <= bj
  } else {
    m0 = blockIdx.y * 128; n0 = blockIdx.x * 128;
  }
  const int w = tid >> 6, lane = tid & 63;
  const int wr = w >> 1, wc = w & 1;
  const int l15 = lane & 15, quad = lane >> 4;
  const int lrow8 = lane >> 3;                    // 0..7: staging row within 8-row group
  const int cg = ((lane & 7) ^ lrow8) * 8;        // swizzled global source chunk (ushorts)
  const int xsw = l15 & 7;                        // fragment-read xor
  const int lbase = (w * 32) * 64;                // wave-uniform LDS base offset
  const size_t sK8 = (size_t)8 * K;

  f32x4 acc[4][4];
  if (MODE <= 1) {
    #pragma unroll
    for (int nj = 0; nj < 4; ++nj) {
      float bv = bias[n0 + wc * 64 + nj * 16 + l15];
      #pragma unroll
      for (int mi = 0; mi < 4; ++mi) acc[mi][nj] = (f32x4){bv, bv, bv, bv};
    }
  } else {
    #pragma unroll
    for (int nj = 0; nj < 4; ++nj)
      #pragma unroll
      for (int mi = 0; mi < 4; ++mi) acc[mi][nj] = (f32x4){0.f, 0.f, 0.f, 0.f};
  }

  // per-thread staging source pointers; advance by 64 ushorts per staged tile
  const ushort_t* gA = A  + (size_t)(m0 + w * 32 + lrow8) * K + cg;
  const ushort_t* gB = Bt + (size_t)(n0 + w * 32 + lrow8) * K + cg;

#define STAGE(AS, BS) do {                                                  \
    ushort_t* la_ = &AS[lbase]; ushort_t* lb_ = &BS[lbase];                 \
    _Pragma("unroll")                                                       \
    for (int j_ = 0; j_ < 4; ++j_) {                                        \
      gl_lds16(gA + (size_t)j_ * sK8, la_ + j_ * 8 * 64);                   \
      gl_lds16(gB + (size_t)j_ * sK8, lb_ + j_ * 8 * 64);                   \
    }                                                                       \
    gA += 64; gB += 64;                                                     \
  } while (0)

#define COMPUTE(AS, BS) do {                                                \
    _Pragma("unroll")                                                       \
    for (int kk_ = 0; kk_ < 2; ++kk_) {                                     \
      const int csel_ = ((kk_ * 4 + quad) ^ xsw) * 8;                       \
      bf16x8 af_[4], bf_[4];                                                \
      _Pragma("unroll")                                                     \
      for (int mi_ = 0; mi_ < 4; ++mi_)                                     \
        af_[mi_] = *reinterpret_cast<const bf16x8*>(                        \
            &AS[(wr * 64 + mi_ * 16 + l15) * 64 + csel_]);                  \
      _Pragma("unroll")                                                     \
      for (int nj_ = 0; nj_ < 4; ++nj_)                                     \
        bf_[nj_] = *reinterpret_cast<const bf16x8*>(                        \
            &BS[(wc * 64 + nj_ * 16 + l15) * 64 + csel_]);                  \
      _Pragma("unroll")                                                     \
      for (int mi_ = 0; mi_ < 4; ++mi_)                                     \
        _Pragma("unroll")                                                   \
        for (int nj_ = 0; nj_ < 4; ++nj_)                                   \
          acc[mi_][nj_] = __builtin_amdgcn_mfma_f32_16x16x32_bf16(          \
              af_[mi_], bf_[nj_], acc[mi_][nj_], 0, 0, 0);                  \
    }                                                                       \
  } while (0)

  // prologue: stage tiles 0 and 1 (16 loads/wave in flight)
  STAGE(As0, Bs0);
  STAGE(As1, Bs1);

  const int nt = K >> 6;   // even, >= 8 for all call sites
  for (int t = 0; t < nt - 2; t += 2) {
    VMWAIT(8);                        // tile t landed; tile t+1 stays in flight
    __builtin_amdgcn_s_barrier();
    COMPUTE(As0, Bs0);                // compute tile t
    __builtin_amdgcn_s_barrier();     // join: all waves done reading buf0
    STAGE(As0, Bs0);                  // prefetch tile t+2
    VMWAIT(8);                        // tile t+1 landed; tile t+2 in flight
    __builtin_amdgcn_s_barrier();
    COMPUTE(As1, Bs1);                // compute tile t+1
    __builtin_amdgcn_s_barrier();     // join: all waves done reading buf1
    STAGE(As1, Bs1);                  // prefetch tile t+3
  }
  // tail: tiles nt-2 (buf0) and nt-1 (buf1) staged, nothing more to prefetch
  VMWAIT(8);
  __builtin_amdgcn_s_barrier();
  COMPUTE(As0, Bs0);
  VMWAIT(0);
  __builtin_amdgcn_s_barrier();      // <- after this barrier As0/Bs0 have no readers
  COMPUTE(As1, Bs1);

#undef STAGE
#undef COMPUTE

  ushort_t* Cb = (ushort_t*)Cout + (size_t)blockIdx.z * sCz;
  float*    Cf = (float*)Cout    + (size_t)blockIdx.z * sCz;

  if (MODE == 6) {
    // symmetric exp-scores epilogue.
    float* rs = rsums + (size_t)blockIdx.z * SQ;
    const bool offdiag = (m0 != n0);
    // mirror staging half-tile: wc=0 half -> As0, wc=1 half -> Bs0 (both dead).
    // element (c=cl in [0,64), r=rl in [0,128)) at cl*128 + (rl ^ ((cl&7)<<4)).
    ushort_t* mir = (wc == 0) ? As0 : Bs0;
    float colpart[4] = {0.f, 0.f, 0.f, 0.f};   // per-nj partial column sums
    #pragma unroll
    for (int mi = 0; mi < 4; ++mi)
      #pragma unroll
      for (int r = 0; r < 4; ++r) {
        int rl = wr * 64 + mi * 16 + quad * 4 + r;
        int gr = m0 + rl;
        float s = 0.f;
        #pragma unroll
        for (int nj = 0; nj < 4; ++nj) {
          int cl = nj * 16 + l15;
          int gc = n0 + wc * 64 + cl;
          float e = exp2f(acc[mi][nj][r] * scale);   // scale includes log2(e)
          ushort_t ub = f2bfu(e);
          Cb[(size_t)gr * N + gc] = ub;
          if (offdiag) mir[cl * 128 + (rl ^ ((cl & 7) << 4))] = ub;
          float er = bfu2f(ub);                      // sum the ROUNDED values
          s += er;
          colpart[nj] += er;
        }
        #pragma unroll
        for (int m_ = 1; m_ < 16; m_ <<= 1) s += __shfl_xor(s, m_);
        if (l15 == 0) atomicAdd(&rs[gr], s);
      }
    if (offdiag) {
      #pragma unroll
      for (int nj = 0; nj < 4; ++nj) {
        float cs = colpart[nj];
        cs += __shfl_xor(cs, 16);                    // reduce over quad lanes
        cs += __shfl_xor(cs, 32);
        if (quad == 0) atomicAdd(&rs[n0 + wc * 64 + nj * 16 + l15], cs);
      }
      __syncthreads();                               // mirror halves complete
      // coalesced mirror write-out: thread -> mirror row (tid>>1), 64-col seg
      int row = tid >> 1, seg = tid & 1;             // row in [0,128)
      const ushort_t* src = (row < 64) ? As0 : Bs0;
      int rl2 = row & 63;
      ushort_t* dst = &Cb[(size_t)(n0 + row) * N + m0 + seg * 64];
      #pragma unroll
      for (int h = 0; h < 4; ++h) {
        int c0 = seg * 64 + h * 16;
        int sb = rl2 * 128 + (c0 ^ ((rl2 & 7) << 4));  // 16-aligned run stays contiguous
        uint4 v0 = *reinterpret_cast<const uint4*>(&src[sb]);
        uint4 v1 = *reinterpret_cast<const uint4*>(&src[sb + 8]);
        *reinterpret_cast<uint4*>(&dst[h * 16])     = v0;
        *reinterpret_cast<uint4*>(&dst[h * 16 + 8]) = v1;
      }
    }
  } else {
    const float* rsr = rsums + (size_t)blockIdx.z * SQ;  // MODE 5 only
    #pragma unroll
    for (int mi = 0; mi < 4; ++mi)
      #pragma unroll
      for (int nj = 0; nj < 4; ++nj) {
        int gc = n0 + wc * 64 + nj * 16 + l15;
        #pragma unroll
        for (int r = 0; r < 4; ++r) {
          int gr = m0 + wr * 64 + mi * 16 + quad * 4 + r;
          float v = acc[mi][nj][r];
          if (MODE == 0) {
            Cb[(size_t)gr * N + gc] = f2bfu(gelu_tanh(v));
          } else if (MODE == 1) {
            Cf[(size_t)gr * N + gc] = v;
          } else if (MODE == 5) {
            Cf[(size_t)gr * N + gc] = v * __builtin_amdgcn_rcpf(rsr[gr]);
          } else {
            Cf[(size_t)gr * N + gc] = v;
          }
        }
      }
  }
}

// ---- LN1 -> bf16 q ----
__global__ __launch_bounds__(256) void k_ln1b(const float* __restrict__ x,
                                              const float* __restrict__ attn,
                                              const float* __restrict__ g,
                                              const float* __restrict__ be,
                                              ushort_t* __restrict__ qbf) {
  size_t base = (size_t)blockIdx.x * D_;
  int tid = threadIdx.x;
  __shared__ float rl[8];
  float v0 = x[base + tid] + attn[base + tid];
  float v1 = x[base + tid + 256] + attn[base + tid + 256];
  float s = v0 + v1, sq = v0 * v0 + v1 * v1;
  #pragma unroll
  for (int o = 32; o > 0; o >>= 1) { s += __shfl_down(s, o); sq += __shfl_down(sq, o); }
  int lane = tid & 63, wid = tid >> 6;
  if (lane == 0) { rl[wid] = s; rl[4 + wid] = sq; }
  __syncthreads();
  s = rl[0] + rl[1] + rl[2] + rl[3];
  sq = rl[4] + rl[5] + rl[6] + rl[7];
  float mean = s * (1.0f / 512.0f);
  float var = sq * (1.0f / 512.0f) - mean * mean;
  float rstd = rsqrtf(var + 1e-5f);
  qbf[base + tid]       = f2bfu((v0 - mean) * rstd * g[tid] + be[tid]);
  qbf[base + tid + 256] = f2bfu((v1 - mean) * rstd * g[tid + 256] + be[tid + 256]);
}

// ---- fast LN3: one block per (b,si); LDS transpose -> fully coalesced output ----
__global__ __launch_bounds__(256) void k_ln3_f(const float* __restrict__ y,
                                               const ushort_t* __restrict__ qbf,
                                               const float* __restrict__ g3,
                                               const float* __restrict__ be3,
                                               float* __restrict__ out) {
  __shared__ float ynorm[8][512];
  const int tid = threadIdx.x;
  const int w = tid >> 6, lane = tid & 63;
  #pragma unroll
  for (int rr = 0; rr < 2; ++rr) {
    int l = 2 * w + rr;
    size_t t = (size_t)blockIdx.x * 8 + l;
    float v[8];
    float s = 0.f, sq = 0.f;
    #pragma unroll
    for (int j = 0; j < 8; ++j) {
      int k = lane + 64 * j;
      v[j] = y[t * D_ + k] + bfu2f(qbf[t * D_ + k]);
      s += v[j]; sq += v[j] * v[j];
    }
    #pragma unroll
    for (int o = 32; o > 0; o >>= 1) { s += __shfl_down(s, o); sq += __shfl_down(sq, o); }
    s = __shfl(s, 0); sq = __shfl(sq, 0);
    float mean = s * (1.0f / 512.0f);
    float var = sq * (1.0f / 512.0f) - mean * mean;
    float rstd = rsqrtf(var + 1e-5f);
    #pragma unroll
    for (int j = 0; j < 8; ++j) {
      int k = lane + 64 * j;
      ynorm[l][k] = (v[j] - mean) * rstd * g3[k] + be3[k];
    }
  }
  __syncthreads();
  float* ob = out + (size_t)blockIdx.x * 4096;
  #pragma unroll
  for (int kk = 0; kk < 2; ++kk) {
    int k = tid * 2 + kk;
    float4 lo = make_float4(ynorm[0][k], ynorm[1][k], ynorm[2][k], ynorm[3][k]);
    float4 hi = make_float4(ynorm[4][k], ynorm[5][k], ynorm[6][k], ynorm[7][k]);
    *reinterpret_cast<float4*>(ob + (size_t)k * 8)     = lo;
    *reinterpret_cast<float4*>(ob + (size_t)k * 8 + 4) = hi;
  }
}

// ================= slow-path fp32 kernels (fallback only) =================
#define TS 64
#define KT 16
__global__ __launch_bounds__(256) void k_build_x_s(const float* __restrict__ lags,
                                                   float* __restrict__ x, int b_base) {
  int idx = blockIdx.x * 256 + threadIdx.x;
  int k = idx & (D_ - 1);
  int r = idx >> 9;
  int b = b_base + r / SQ;
  int t = r - (r / SQ) * SQ;
  int si = t >> 3, l = t & 7;
  size_t src = (((size_t)(b * S_ + si) * D_ + k) << 3) + l;
  x[idx] = lags[src];
}

__global__ __launch_bounds__(256) void k_scores(const float* __restrict__ x,
                                                float* __restrict__ sc, int b_base) {
  const float* A = x;
  float* C = sc;
  __shared__ float As[TS][KT + 1];
  __shared__ float Bs[TS][KT + 1];
  int tx = threadIdx.x & 15, ty = threadIdx.x >> 4;
  int j0 = blockIdx.x * TS, i0 = blockIdx.y * TS;
  float acc[4][4] = {};
  int lk = threadIdx.x & 15, lr = threadIdx.x >> 4;
  for (int k0 = 0; k0 < D_; k0 += KT) {
    #pragma unroll
    for (int it = 0; it < 4; ++it) {
      As[lr + 16 * it][lk] = A[(size_t)(i0 + lr + 16 * it) * D_ + k0 + lk];
      Bs[lr + 16 * it][lk] = A[(size_t)(j0 + lr + 16 * it) * D_ + k0 + lk];
    }
    __syncthreads();
    #pragma unroll
    for (int kk = 0; kk < KT; ++kk) {
      float a[4], bb[4];
      #pragma unroll
      for (int r = 0; r < 4; ++r) a[r] = As[ty * 4 + r][kk];
      #pragma unroll
      for (int c = 0; c < 4; ++c) bb[c] = Bs[tx * 4 + c][kk];
      #pragma unroll
      for (int r = 0; r < 4; ++r)
        #pragma unroll
        for (int c = 0; c < 4; ++c) acc[r][c] = fmaf(a[r], bb[c], acc[r][c]);
    }
    __syncthreads();
  }
  #pragma unroll
  for (int r = 0; r < 4; ++r) {
    float4 v = make_float4(acc[r][0]*SCALE_QK, acc[r][1]*SCALE_QK,
                           acc[r][2]*SCALE_QK, acc[r][3]*SCALE_QK);
    *reinterpret_cast<float4*>(&C[(size_t)(i0 + ty*4 + r) * SQ + j0 + tx*4]) = v;
  }
}

__global__ __launch_bounds__(256) void k_softmax(float* __restrict__ sc) {
  float* row = sc + (size_t)blockIdx.x * SQ;
  int tid = threadIdx.x;
  __shared__ float red[8];
  float m = -1e30f;
  for (int j = tid; j < SQ; j += 256) m = fmaxf(m, row[j]);
  #pragma unroll
  for (int o = 32; o > 0; o >>= 1) m = fmaxf(m, __shfl_down(m, o));
  if ((tid & 63) == 0) red[tid >> 6] = m;
  __syncthreads();
  m = fmaxf(fmaxf(red[0], red[1]), fmaxf(red[2], red[3]));
  __syncthreads();
  float ssum = 0.f;
  for (int j = tid; j < SQ; j += 256) { float e = expf(row[j] - m); row[j] = e; ssum += e; }
  #pragma unroll
  for (int o = 32; o > 0; o >>= 1) ssum += __shfl_down(ssum, o);
  if ((tid & 63) == 0) red[4 + (tid >> 6)] = ssum;
  __syncthreads();
  float inv = 1.0f / (red[4] + red[5] + red[6] + red[7]);
  for (int j = tid; j < SQ; j += 256) row[j] *= inv;
}

__global__ __launch_bounds__(256) void k_attn(const float* __restrict__ x,
                                              const float* __restrict__ sc,
                                              float* __restrict__ attn) {
  const float* X = x;
  const float* P = sc;
  float* O = attn;
  __shared__ float Ps[TS][KT + 1];
  __shared__ float Xs[KT][TS];
  int tx = threadIdx.x & 15, ty = threadIdx.x >> 4;
  int j0 = blockIdx.x * TS, i0 = blockIdx.y * TS;
  float acc[4][4] = {};
  int lk = threadIdx.x & 15, lr = threadIdx.x >> 4;
  int lc = threadIdx.x & 63, lrow = threadIdx.x >> 6;
  for (int k0 = 0; k0 < SQ; k0 += KT) {
    #pragma unroll
    for (int it = 0; it < 4; ++it)
      Ps[lr + 16 * it][lk] = P[(size_t)(i0 + lr + 16 * it) * SQ + k0 + lk];
    #pragma unroll
    for (int it = 0; it < 4; ++it)
      Xs[lrow + 4 * it][lc] = X[(size_t)(k0 + lrow + 4 * it) * D_ + j0 + lc];
    __syncthreads();
    #pragma unroll
    for (int kk = 0; kk < KT; ++kk) {
      float a[4], bb[4];
      #pragma unroll
      for (int r = 0; r < 4; ++r) a[r] = Ps[ty * 4 + r][kk];
      #pragma unroll
      for (int c = 0; c < 4; ++c) bb[c] = Xs[kk][tx * 4 + c];
      #pragma unroll
      for (int r = 0; r < 4; ++r)
        #pragma unroll
        for (int c = 0; c < 4; ++c) acc[r][c] = fmaf(a[r], bb[c], acc[r][c]);
    }
    __syncthreads();
  }
  #pragma unroll
  for (int r = 0; r < 4; ++r) {
    float4 v = make_float4(acc[r][0], acc[r][1], acc[r][2], acc[r][3]);
    *reinterpret_cast<float4*>(&O[(size_t)(i0 + ty*4 + r) * D_ + j0 + tx*4]) = v;
  }
}

__global__ __launch_bounds__(256) void k_ln1(const float* __restrict__ x,
                                             const float* __restrict__ attn,
                                             const float* __restrict__ g,
                                             const float* __restrict__ be,
                                             float* __restrict__ qout) {
  size_t base = (size_t)blockIdx.x * D_;
  int tid = threadIdx.x;
  __shared__ float rl[8];
  float v0 = x[base + tid] + attn[base + tid];
  float v1 = x[base + tid + 256] + attn[base + tid + 256];
  float s = v0 + v1, sq = v0 * v0 + v1 * v1;
  #pragma unroll
  for (int o = 32; o > 0; o >>= 1) { s += __shfl_down(s, o); sq += __shfl_down(sq, o); }
  int lane = tid & 63, wid = tid >> 6;
  if (lane == 0) { rl[wid] = s; rl[4 + wid] = sq; }
  __syncthreads();
  s = rl[0] + rl[1] + rl[2] + rl[3];
  sq = rl[4] + rl[5] + rl[6] + rl[7];
  float mean = s * (1.0f / 512.0f);
  float var = sq * (1.0f / 512.0f) - mean * mean;
  float rstd = rsqrtf(var + 1e-5f);
  qout[base + tid]       = (v0 - mean) * rstd * g[tid] + be[tid];
  qout[base + tid + 256] = (v1 - mean) * rstd * g[tid + 256] + be[tid + 256];
}

__global__ __launch_bounds__(256, 2) void k_ffn(
    const float* __restrict__ q,
    const float* __restrict__ W1, const float* __restrict__ b1,
    const float* __restrict__ W2, const float* __restrict__ b2,
    const float* __restrict__ g3, const float* __restrict__ be3,
    float* __restrict__ out, int row_base)
{
  __shared__ float qs[8][D_];
  __shared__ float mid[8][H_];
  const int tid = threadIdx.x;
  const int row0 = blockIdx.x * 8;
  for (int idx = tid; idx < 8 * D_; idx += 256)
    qs[idx >> 9][idx & (D_ - 1)] = q[(size_t)row0 * D_ + idx];
  __syncthreads();
  float acc[8][8];
  {
    float4 bA = *reinterpret_cast<const float4*>(b1 + (tid << 3));
    float4 bB = *reinterpret_cast<const float4*>(b1 + (tid << 3) + 4);
    float bv[8] = {bA.x, bA.y, bA.z, bA.w, bB.x, bB.y, bB.z, bB.w};
    #pragma unroll
    for (int jj = 0; jj < 8; ++jj)
      #pragma unroll
      for (int r = 0; r < 8; ++r) acc[jj][r] = bv[jj];
  }
  for (int k4 = 0; k4 < D_ / 4; ++k4) {
    float4 qv[8];
    #pragma unroll
    for (int r = 0; r < 8; ++r)
      qv[r] = *reinterpret_cast<const float4*>(&qs[r][k4 << 2]);
    #pragma unroll
    for (int kk = 0; kk < 4; ++kk) {
      const int k = (k4 << 2) + kk;
      float4 wA = *reinterpret_cast<const float4*>(W1 + (size_t)k * H_ + (tid << 3));
      float4 wB = *reinterpret_cast<const float4*>(W1 + (size_t)k * H_ + (tid << 3) + 4);
      float wv[8] = {wA.x, wA.y, wA.z, wA.w, wB.x, wB.y, wB.z, wB.w};
      #pragma unroll
      for (int r = 0; r < 8; ++r) {
        float qk = (kk == 0) ? qv[r].x : (kk == 1) ? qv[r].y : (kk == 2) ? qv[r].z : qv[r].w;
        #pragma unroll
        for (int jj = 0; jj < 8; ++jj) acc[jj][r] = fmaf(qk, wv[jj], acc[jj][r]);
      }
    }
  }
  #pragma unroll
  for (int jj = 0; jj < 8; ++jj)
    #pragma unroll
    for (int r = 0; r < 8; ++r) {
      float v = acc[jj][r];
      mid[r][(tid << 3) + jj] = 0.5f * v * (1.0f + erff(v * 0.70710678118654752f));
    }
  __syncthreads();
  float acc2[8][2];
  {
    float b20 = b2[tid << 1], b21 = b2[(tid << 1) + 1];
    #pragma unroll
    for (int r = 0; r < 8; ++r) { acc2[r][0] = b20; acc2[r][1] = b21; }
  }
  for (int j4 = 0; j4 < H_ / 4; ++j4) {
    float4 mv[8];
    #pragma unroll
    for (int r = 0; r < 8; ++r)
      mv[r] = *reinterpret_cast<const float4*>(&mid[r][j4 << 2]);
    #pragma unroll
    for (int kk = 0; kk < 4; ++kk) {
      const int j = (j4 << 2) + kk;
      float2 wv = *reinterpret_cast<const float2*>(W2 + (size_t)j * D_ + (tid << 1));
      #pragma unroll
      for (int r = 0; r < 8; ++r) {
        float m = (kk == 0) ? mv[r].x : (kk == 1) ? mv[r].y : (kk == 2) ? mv[r].z : mv[r].w;
        acc2[r][0] = fmaf(m, wv.x, acc2[r][0]);
        acc2[r][1] = fmaf(m, wv.y, acc2[r][1]);
      }
    }
  }
  __syncthreads();
  float* ys = &mid[0][0];
  #pragma unroll
  for (int r = 0; r < 8; ++r) {
    ys[r * D_ + (tid << 1)]     = qs[r][(tid << 1)]     + acc2[r][0];
    ys[r * D_ + (tid << 1) + 1] = qs[r][(tid << 1) + 1] + acc2[r][1];
  }
  __syncthreads();
  float g3a = g3[tid],  g3b = g3[tid + 256];
  float be3a = be3[tid], be3b = be3[tid + 256];
  float* rl = &qs[0][0];
  for (int r = 0; r < 8; ++r) {
    float v0 = ys[r * D_ + tid], v1 = ys[r * D_ + tid + 256];
    float s = v0 + v1, sq = v0 * v0 + v1 * v1;
    #pragma unroll
    for (int o = 32; o > 0; o >>= 1) { s += __shfl_down(s, o); sq += __shfl_down(sq, o); }
    int lane = tid & 63, wid = tid >> 6;
    if (lane == 0) { rl[wid] = s; rl[4 + wid] = sq; }
    __syncthreads();
    s = rl[0] + rl[1] + rl[2] + rl[3];
    sq = rl[4] + rl[5] + rl[6] + rl[7];
    __syncthreads();
    float mean = s * (1.0f / 512.0f);
    float var = sq * (1.0f / 512.0f) - mean * mean;
    float rstd = rsqrtf(var + 1e-5f);
    int t = row_base + row0 + r;
    int b = t / SQ, tt = t - b * SQ;
    int si = tt >> 3, l = tt & 7;
    size_t ob = (((size_t)(b * S_ + si) * D_) << 3) + l;
    out[ob + ((size_t)tid << 3)]         = (v0 - mean) * rstd * g3a + be3a;
    out[ob + ((size_t)(tid + 256) << 3)] = (v1 - mean) * rstd * g3b + be3b;
  }
}

extern "C" void kernel_launch(void* const* d_in, const int* in_sizes, int n_in,
                              void* d_out, int out_size, void* d_ws, size_t ws_size,
                              hipStream_t stream) {
  const float* lags   = (const float*)d_in[0];
  const float* gamma1 = (const float*)d_in[1];
  const float* beta1  = (const float*)d_in[2];
  const float* W1     = (const float*)d_in[3];
  const float* b1     = (const float*)d_in[4];
  const float* W2     = (const float*)d_in[5];
  const float* b2     = (const float*)d_in[6];
  const float* g3     = (const float*)d_in[7];
  const float* be3    = (const float*)d_in[8];
  float* out = (float*)d_out;

  float* ws = (float*)d_ws;
  const size_t NX  = (size_t)B_ * SQ * D_;   // 6,291,456
  const size_t NXB = (size_t)SQ * D_;        //   786,432
  const size_t NS  = (size_t)SQ * SQ;        // 2,359,296

  const size_t need_full = (3 * NX + 8 * NS) * sizeof(float);  // ~151 MB (proven available)

  if (ws_size >= need_full) {
    // ---- fast path layout (~130 MB) ----
    float* x        = ws;                                   // NX f32
    float* attn     = x + NX;                               // NX f32 (later: y)
    ushort_t* q_bf  = (ushort_t*)(attn + NX);               // NX us
    ushort_t* w1t   = q_bf + NX;                            // H*D us
    ushort_t* w2t   = w1t + (size_t)H_ * D_;                // H*D us
    float* rowsum   = (float*)(w2t + (size_t)H_ * D_);      // B*SQ f32 (48 KB)
    ushort_t* region = (ushort_t*)(rowsum + (size_t)B_ * SQ); // 8*NS + 2*NX us
    ushort_t* sc_bf = region;                               // exp-scores, bf16
    ushort_t* x_bf  = region + 8 * NS;
    ushort_t* xT_bf = x_bf + NX;
    ushort_t* mid_bf = region;                              // aliases dead sc/x_bf/xT_bf

    k_build_x_f<<<dim3(B_ * S_), 256, 0, stream>>>(lags, x, x_bf, xT_bf, rowsum);
    k_wt2<<<dim3(512), 256, 0, stream>>>(W1, w1t, W2, w2t);
    // P = exp(scale * X X^T) -> bf16 (SYMMETRIC: 78 triangular blocks/batch,
    // off-diagonal tiles mirrored via LDS transpose, coalesced write-out);
    // rowsum accumulated (row + column sums). No max-sub needed: scores <= ~31.
    k_gemm<6><<<dim3(78, 1, B_), 256, 0, stream>>>(
        x_bf, x_bf, nullptr, rowsum, sc_bf, SQ, D_, SQ, NXB, NXB, NS, SCALE_QK2);
    // attn = (P @ X) / rowsum -> f32  (softmax normalization folded in)
    k_gemm<5><<<dim3(D_ / 128, SQ / 128, B_), 256, 0, stream>>>(
        sc_bf, xT_bf, nullptr, rowsum, attn, SQ, SQ, D_, NS, NXB, NXB, 1.0f);
    k_ln1b<<<dim3(NROW), 256, 0, stream>>>(x, attn, gamma1, beta1, q_bf);
    // mid = gelu(q @ W1 + b1) -> bf16
    k_gemm<0><<<dim3(H_ / 128, NROW / 128, 1), 256, 0, stream>>>(
        q_bf, w1t, b1, nullptr, mid_bf, NROW, D_, H_, 0, 0, 0, 1.0f);
    // y = mid @ W2 + b2 -> f32 (attn buffer)
    k_gemm<1><<<dim3(D_ / 128, NROW / 128, 1), 256, 0, stream>>>(
        mid_bf, w2t, b2, nullptr, attn, NROW, H_, D_, 0, 0, 0, 1.0f);
    k_ln3_f<<<dim3(B_ * S_), 256, 0, stream>>>(attn, q_bf, g3, be3, out);
  } else {
    // ---- minimal-footprint fallback (fp32, per-batch) ----
    float* xb   = ws;
    float* sc   = xb + NXB;
    float* atb  = sc + NS;
    float* qb   = atb + NXB;
    for (int b = 0; b < B_; ++b) {
      k_build_x_s<<<dim3((unsigned)(NXB / 256)), 256, 0, stream>>>(lags, xb, b);
      k_scores<<<dim3(SQ / TS, SQ / TS, 1), 256, 0, stream>>>(xb, sc, b);
      k_softmax<<<dim3(SQ, 1, 1), 256, 0, stream>>>(sc);
      k_attn<<<dim3(D_ / TS, SQ / TS, 1), 256, 0, stream>>>(xb, sc, atb);
      k_ln1<<<dim3(SQ), 256, 0, stream>>>(xb, atb, gamma1, beta1, qb);
      k_ffn<<<dim3(SQ / 8), 256, 0, stream>>>(qb, W1, b1, W2, b2, g3, be3, out, b * SQ);
    }
  }
}

// Round 12
// 277.155 us; speedup vs baseline: 1.0678x; 1.0263x over previous
//
#include <hip/hip_runtime.h>
#include <hip/hip_bf16.h>
#include <math.h>

#define B_ 8
#define S_ 192
#define D_ 512
#define L_ 8
#define SQ 1536   // S_*L_
#define H_ 2048
#define NROW (B_*SQ)   // 12288
#define SCALE_QK 0.04419417382415922f   // 1/sqrt(512)
#define SCALE_QK2 0.06377551974755906f  // SCALE_QK * log2(e)

typedef unsigned short ushort_t;
typedef unsigned int uint_t;
typedef __attribute__((ext_vector_type(8))) short bf16x8;
typedef __attribute__((ext_vector_type(4))) float f32x4;

__device__ __forceinline__ float bfu2f(ushort_t u) { return __uint_as_float((unsigned)u << 16); }
__device__ __forceinline__ ushort_t f2bfu(float f) {
  __hip_bfloat16 h = __float2bfloat16(f);
  return *reinterpret_cast<ushort_t*>(&h);
}

// tanh-form GELU: 0.5x(1+tanh(0.79788456(x+0.044715x^3))), max |err| ~3e-4.
__device__ __forceinline__ float gelu_tanh(float x) {
  float x2 = x * x;
  float u2 = x * fmaf(0.0713548162f, x2, 1.5957691216f);
  float e = __expf(u2);                       // e^(2u)
  float r = fmaf(-2.0f, __builtin_amdgcn_rcpf(e + 1.0f), 1.0f);  // tanh(u)
  float hx = 0.5f * x;
  return fmaf(hx, r, hx);
}

// async global->LDS, 16B per lane; LDS dest = wave-uniform base + lane*16
__device__ __forceinline__ void gl_lds16(const ushort_t* g, ushort_t* l) {
  __builtin_amdgcn_global_load_lds(
      (const __attribute__((address_space(1))) unsigned int*)g,
      (__attribute__((address_space(3))) unsigned int*)l, 16, 0, 0);
}

// counted vmcnt wait: leaves N newest VMEM ops in flight (T4).
#define VMWAIT(N) asm volatile("s_waitcnt vmcnt(" #N ")" ::: "memory")

// ---- prep kernel: blocks [0,1536) build x / x_bf / xT_bf + zero rowsum;
//      blocks [1536,2048) cast+transpose W1/W2 -> bf16 (merged, saves a dispatch)
__global__ __launch_bounds__(256) void k_prep(const float* __restrict__ lags,
                                              float* __restrict__ x,
                                              ushort_t* __restrict__ x_bf,
                                              ushort_t* __restrict__ xT,
                                              float* __restrict__ rowsum,
                                              const float* __restrict__ W1,
                                              ushort_t* __restrict__ w1t,
                                              const float* __restrict__ W2,
                                              ushort_t* __restrict__ w2t) {
  __shared__ float tileF[512][9];      // build_x scratch (18 KB)
  __shared__ ushort_t tileW[64][65];   // wt scratch (8.3 KB)
  const int tid = threadIdx.x;
  if (blockIdx.x < 1536) {
    const int bx = blockIdx.x;
    if (tid < 8) rowsum[(size_t)bx * 8 + tid] = 0.f;
    const float* in = lags + (size_t)bx * 4096;
    #pragma unroll
    for (int it = 0; it < 4; ++it) {
      int f = (tid + it * 256) * 4;
      float4 v = *reinterpret_cast<const float4*>(in + f);
      int k = f >> 3, l0 = f & 7;
      tileF[k][l0] = v.x; tileF[k][l0 + 1] = v.y; tileF[k][l0 + 2] = v.z; tileF[k][l0 + 3] = v.w;
    }
    __syncthreads();
    const int l = tid >> 5, kbase = tid & 31;
    const size_t r = (size_t)bx * 8 + l;
    #pragma unroll
    for (int j = 0; j < 16; ++j) {
      int k = kbase + 32 * j;
      float v = tileF[k][l];
      x[r * D_ + k] = v;
      x_bf[r * D_ + k] = f2bfu(v);
    }
    const int b = bx / S_, si = bx - b * S_;
    #pragma unroll
    for (int dd = 0; dd < 2; ++dd) {
      int d = tid + dd * 256;
      uint_t pk[4];
      #pragma unroll
      for (int j = 0; j < 4; ++j) {
        uint_t lo = f2bfu(tileF[d][2 * j]);
        uint_t hi = f2bfu(tileF[d][2 * j + 1]);
        pk[j] = (hi << 16) | lo;
      }
      uint_t* dst = (uint_t*)(xT + ((size_t)b * D_ + d) * SQ + si * 8);
      *reinterpret_cast<uint4*>(dst) = make_uint4(pk[0], pk[1], pk[2], pk[3]);
    }
  } else {
    int id = blockIdx.x - 1536;
    const float* W; ushort_t* Wt; int K, N, n0, k0;
    if (id < 256) {
      W = W1; Wt = w1t; K = D_; N = H_;
      n0 = (id & 31) * 64; k0 = (id >> 5) * 64;
    } else {
      id -= 256;
      W = W2; Wt = w2t; K = H_; N = D_;
      n0 = (id & 7) * 64; k0 = (id >> 3) * 64;
    }
    for (int i = tid; i < 4096; i += 256) {
      int kk = i >> 6, nn = i & 63;
      tileW[nn][kk] = f2bfu(W[(size_t)(k0 + kk) * N + n0 + nn]);
    }
    __syncthreads();
    for (int i = tid; i < 4096; i += 256) {
      int nn = i >> 6, kk = i & 63;
      Wt[(size_t)(n0 + nn) * K + k0 + kk] = tileW[nn][kk];
    }
  }
}

// ---- bf16 MFMA GEMM (r3 core: 128x128 tile, 4 waves, BK=64, 2-buffer
// counted-vmcnt pipeline, zero-conflict swizzled LDS):  C = A[M,K] @ Bt[N,K]^T
// MODE 0: +bias, gelu -> bf16      | 1: +bias -> f32
// MODE 5: v * rcp(rsums[row]) -> f32   (softmax normalization folded in)
// MODE 6: SYMMETRIC exp-scores (A==Bt): triangular grid blockIdx.x in [0,78)
//         decodes (bi<=bj); stores bf16 exp(scale*v) at [bi,bj]; mirrored tile
//         [bj,bi] staged in LDS (As0/Bs0, dead after K-loop; XOR-swizzled),
//         written coalesced. Row sums via l15-reduce + atomicAdd; mirror row
//         sums via quad-reduce column sums + atomicAdd.
// bias: MODE<=1 only. rsums: MODE 6 written / MODE 5 read; batch stride SQ.
template<int MODE>
__global__ __launch_bounds__(256) void k_gemm(const ushort_t* __restrict__ A,
                                              const ushort_t* __restrict__ Bt,
                                              const float* __restrict__ bias,
                                              float* __restrict__ rsums,
                                              void* __restrict__ Cout,
                                              int M, int K, int N,
                                              size_t sAz, size_t sBz, size_t sCz,
                                              float scale) {
  A  += (size_t)blockIdx.z * sAz;
  Bt += (size_t)blockIdx.z * sBz;
  __shared__ ushort_t As0[128 * 64];   // 16 KB each, 64 KB total -> 2 blocks/CU
  __shared__ ushort_t As1[128 * 64];
  __shared__ ushort_t Bs0[128 * 64];
  __shared__ ushort_t Bs1[128 * 64];
  const int tid = threadIdx.x;
  int m0, n0;
  if (MODE == 6) {
    int lidx = blockIdx.x, bi = 0;
    while (lidx >= 12 - bi) { lidx -= 12 - bi; ++bi; }   // 12 = SQ/128 panels
    m0 = bi * 128; n0 = (bi + lidx) * 128;               // bi <= bj
  } else {
    m0 = blockIdx.y * 128; n0 = blockIdx.x * 128;
  }
  const int w = tid >> 6, lane = tid & 63;
  const int wr = w >> 1, wc = w & 1;
  const int l15 = lane & 15, quad = lane >> 4;
  const int lrow8 = lane >> 3;                    // 0..7: staging row within 8-row group
  const int cg = ((lane & 7) ^ lrow8) * 8;        // swizzled global source chunk (ushorts)
  const int xsw = l15 & 7;                        // fragment-read xor
  const int lbase = (w * 32) * 64;                // wave-uniform LDS base offset
  const size_t sK8 = (size_t)8 * K;

  f32x4 acc[4][4];
  if (MODE <= 1) {
    #pragma unroll
    for (int nj = 0; nj < 4; ++nj) {
      float bv = bias[n0 + wc * 64 + nj * 16 + l15];
      #pragma unroll
      for (int mi = 0; mi < 4; ++mi) acc[mi][nj] = (f32x4){bv, bv, bv, bv};
    }
  } else {
    #pragma unroll
    for (int nj = 0; nj < 4; ++nj)
      #pragma unroll
      for (int mi = 0; mi < 4; ++mi) acc[mi][nj] = (f32x4){0.f, 0.f, 0.f, 0.f};
  }

  // per-thread staging source pointers; advance by 64 ushorts per staged tile
  const ushort_t* gA = A  + (size_t)(m0 + w * 32 + lrow8) * K + cg;
  const ushort_t* gB = Bt + (size_t)(n0 + w * 32 + lrow8) * K + cg;

#define STAGE(AS, BS) do {                                                  \
    ushort_t* la_ = &AS[lbase]; ushort_t* lb_ = &BS[lbase];                 \
    _Pragma("unroll")                                                       \
    for (int j_ = 0; j_ < 4; ++j_) {                                        \
      gl_lds16(gA + (size_t)j_ * sK8, la_ + j_ * 8 * 64);                   \
      gl_lds16(gB + (size_t)j_ * sK8, lb_ + j_ * 8 * 64);                   \
    }                                                                       \
    gA += 64; gB += 64;                                                     \
  } while (0)

#define COMPUTE(AS, BS) do {                                                \
    _Pragma("unroll")                                                       \
    for (int kk_ = 0; kk_ < 2; ++kk_) {                                     \
      const int csel_ = ((kk_ * 4 + quad) ^ xsw) * 8;                       \
      bf16x8 af_[4], bf_[4];                                                \
      _Pragma("unroll")                                                     \
      for (int mi_ = 0; mi_ < 4; ++mi_)                                     \
        af_[mi_] = *reinterpret_cast<const bf16x8*>(                        \
            &AS[(wr * 64 + mi_ * 16 + l15) * 64 + csel_]);                  \
      _Pragma("unroll")                                                     \
      for (int nj_ = 0; nj_ < 4; ++nj_)                                     \
        bf_[nj_] = *reinterpret_cast<const bf16x8*>(                        \
            &BS[(wc * 64 + nj_ * 16 + l15) * 64 + csel_]);                  \
      _Pragma("unroll")                                                     \
      for (int mi_ = 0; mi_ < 4; ++mi_)                                     \
        _Pragma("unroll")                                                   \
        for (int nj_ = 0; nj_ < 4; ++nj_)                                   \
          acc[mi_][nj_] = __builtin_amdgcn_mfma_f32_16x16x32_bf16(          \
              af_[mi_], bf_[nj_], acc[mi_][nj_], 0, 0, 0);                  \
    }                                                                       \
  } while (0)

  // prologue: stage tiles 0 and 1 (16 loads/wave in flight)
  STAGE(As0, Bs0);
  STAGE(As1, Bs1);

  const int nt = K >> 6;   // even, >= 8 for all call sites
  for (int t = 0; t < nt - 2; t += 2) {
    VMWAIT(8);                        // tile t landed; tile t+1 stays in flight
    __builtin_amdgcn_s_barrier();
    COMPUTE(As0, Bs0);                // compute tile t
    __builtin_amdgcn_s_barrier();     // join: all waves done reading buf0
    STAGE(As0, Bs0);                  // prefetch tile t+2
    VMWAIT(8);                        // tile t+1 landed; tile t+2 in flight
    __builtin_amdgcn_s_barrier();
    COMPUTE(As1, Bs1);                // compute tile t+1
    __builtin_amdgcn_s_barrier();     // join: all waves done reading buf1
    STAGE(As1, Bs1);                  // prefetch tile t+3
  }
  // tail: tiles nt-2 (buf0) and nt-1 (buf1) staged, nothing more to prefetch
  VMWAIT(8);
  __builtin_amdgcn_s_barrier();
  COMPUTE(As0, Bs0);
  VMWAIT(0);
  __builtin_amdgcn_s_barrier();      // <- after this barrier As0/Bs0 have no readers
  COMPUTE(As1, Bs1);

#undef STAGE
#undef COMPUTE

  ushort_t* Cb = (ushort_t*)Cout + (size_t)blockIdx.z * sCz;
  float*    Cf = (float*)Cout    + (size_t)blockIdx.z * sCz;

  if (MODE == 6) {
    // symmetric exp-scores epilogue.
    float* rs = rsums + (size_t)blockIdx.z * SQ;
    const bool offdiag = (m0 != n0);
    // mirror staging half-tile: wc=0 half -> As0, wc=1 half -> Bs0 (both dead).
    // element (c=cl in [0,64), r=rl in [0,128)) at cl*128 + (rl ^ ((cl&7)<<4)).
    ushort_t* mir = (wc == 0) ? As0 : Bs0;
    float colpart[4] = {0.f, 0.f, 0.f, 0.f};   // per-nj partial column sums
    #pragma unroll
    for (int mi = 0; mi < 4; ++mi)
      #pragma unroll
      for (int r = 0; r < 4; ++r) {
        int rl = wr * 64 + mi * 16 + quad * 4 + r;
        int gr = m0 + rl;
        float s = 0.f;
        #pragma unroll
        for (int nj = 0; nj < 4; ++nj) {
          int cl = nj * 16 + l15;
          int gc = n0 + wc * 64 + cl;
          float e = exp2f(acc[mi][nj][r] * scale);   // scale includes log2(e)
          ushort_t ub = f2bfu(e);
          Cb[(size_t)gr * N + gc] = ub;
          if (offdiag) mir[cl * 128 + (rl ^ ((cl & 7) << 4))] = ub;
          float er = bfu2f(ub);                      // sum the ROUNDED values
          s += er;
          colpart[nj] += er;
        }
        #pragma unroll
        for (int m_ = 1; m_ < 16; m_ <<= 1) s += __shfl_xor(s, m_);
        if (l15 == 0) atomicAdd(&rs[gr], s);
      }
    if (offdiag) {
      #pragma unroll
      for (int nj = 0; nj < 4; ++nj) {
        float cs = colpart[nj];
        cs += __shfl_xor(cs, 16);                    // reduce over quad lanes
        cs += __shfl_xor(cs, 32);
        if (quad == 0) atomicAdd(&rs[n0 + wc * 64 + nj * 16 + l15], cs);
      }
      __syncthreads();                               // mirror halves complete
      // coalesced mirror write-out: thread -> mirror row (tid>>1), 64-col seg
      int row = tid >> 1, seg = tid & 1;             // row in [0,128)
      const ushort_t* src = (row < 64) ? As0 : Bs0;
      int rl2 = row & 63;
      ushort_t* dst = &Cb[(size_t)(n0 + row) * N + m0 + seg * 64];
      #pragma unroll
      for (int h = 0; h < 4; ++h) {
        int c0 = seg * 64 + h * 16;
        int sb = rl2 * 128 + (c0 ^ ((rl2 & 7) << 4));  // 16-aligned run stays contiguous
        uint4 v0 = *reinterpret_cast<const uint4*>(&src[sb]);
        uint4 v1 = *reinterpret_cast<const uint4*>(&src[sb + 8]);
        *reinterpret_cast<uint4*>(&dst[h * 16])     = v0;
        *reinterpret_cast<uint4*>(&dst[h * 16 + 8]) = v1;
      }
    }
  } else {
    const float* rsr = rsums + (size_t)blockIdx.z * SQ;  // MODE 5 only
    #pragma unroll
    for (int mi = 0; mi < 4; ++mi)
      #pragma unroll
      for (int nj = 0; nj < 4; ++nj) {
        int gc = n0 + wc * 64 + nj * 16 + l15;
        #pragma unroll
        for (int r = 0; r < 4; ++r) {
          int gr = m0 + wr * 64 + mi * 16 + quad * 4 + r;
          float v = acc[mi][nj][r];
          if (MODE == 0) {
            Cb[(size_t)gr * N + gc] = f2bfu(gelu_tanh(v));
          } else if (MODE == 1) {
            Cf[(size_t)gr * N + gc] = v;
          } else if (MODE == 5) {
            Cf[(size_t)gr * N + gc] = v * __builtin_amdgcn_rcpf(rsr[gr]);
          } else {
            Cf[(size_t)gr * N + gc] = v;
          }
        }
      }
  }
}

// ---- LN1 -> bf16 q: one wave per row, 16B/lane vectorized (G13) ----
__global__ __launch_bounds__(256) void k_ln1b(const float* __restrict__ x,
                                              const float* __restrict__ attn,
                                              const float* __restrict__ g,
                                              const float* __restrict__ be,
                                              ushort_t* __restrict__ qbf) {
  const int w = threadIdx.x >> 6, lane = threadIdx.x & 63;
  const size_t row = (size_t)blockIdx.x * 4 + w;
  const size_t base = row * D_ + lane * 8;
  float4 x0 = *reinterpret_cast<const float4*>(x + base);
  float4 x1 = *reinterpret_cast<const float4*>(x + base + 4);
  float4 a0 = *reinterpret_cast<const float4*>(attn + base);
  float4 a1 = *reinterpret_cast<const float4*>(attn + base + 4);
  float v[8] = {x0.x + a0.x, x0.y + a0.y, x0.z + a0.z, x0.w + a0.w,
                x1.x + a1.x, x1.y + a1.y, x1.z + a1.z, x1.w + a1.w};
  float s = 0.f, sq = 0.f;
  #pragma unroll
  for (int j = 0; j < 8; ++j) { s += v[j]; sq += v[j] * v[j]; }
  #pragma unroll
  for (int o = 32; o > 0; o >>= 1) { s += __shfl_down(s, o); sq += __shfl_down(sq, o); }
  s = __shfl(s, 0); sq = __shfl(sq, 0);
  float mean = s * (1.0f / 512.0f);
  float var = sq * (1.0f / 512.0f) - mean * mean;
  float rstd = rsqrtf(var + 1e-5f);
  const int kb = lane * 8;
  float4 g0 = *reinterpret_cast<const float4*>(g + kb);
  float4 g1 = *reinterpret_cast<const float4*>(g + kb + 4);
  float4 b0 = *reinterpret_cast<const float4*>(be + kb);
  float4 b1 = *reinterpret_cast<const float4*>(be + kb + 4);
  float gv[8] = {g0.x, g0.y, g0.z, g0.w, g1.x, g1.y, g1.z, g1.w};
  float bv[8] = {b0.x, b0.y, b0.z, b0.w, b1.x, b1.y, b1.z, b1.w};
  uint_t u[4];
  #pragma unroll
  for (int p = 0; p < 4; ++p) {
    uint_t lo = f2bfu((v[2*p]   - mean) * rstd * gv[2*p]   + bv[2*p]);
    uint_t hi = f2bfu((v[2*p+1] - mean) * rstd * gv[2*p+1] + bv[2*p+1]);
    u[p] = (hi << 16) | lo;
  }
  *reinterpret_cast<uint4*>(qbf + base) = make_uint4(u[0], u[1], u[2], u[3]);
}

// ---- fast LN3: one block per (b,si); vectorized loads (16B/lane), LDS
// transpose -> fully coalesced output ----
__global__ __launch_bounds__(256) void k_ln3_f(const float* __restrict__ y,
                                               const ushort_t* __restrict__ qbf,
                                               const float* __restrict__ g3,
                                               const float* __restrict__ be3,
                                               float* __restrict__ out) {
  __shared__ float ynorm[8][512];
  const int tid = threadIdx.x;
  const int w = tid >> 6, lane = tid & 63;
  const int kb = lane * 8;
  #pragma unroll
  for (int rr = 0; rr < 2; ++rr) {
    int l = 2 * w + rr;
    size_t t = (size_t)blockIdx.x * 8 + l;
    size_t base = t * D_ + kb;
    float4 y0 = *reinterpret_cast<const float4*>(y + base);
    float4 y1 = *reinterpret_cast<const float4*>(y + base + 4);
    uint4 q = *reinterpret_cast<const uint4*>(qbf + base);
    float v[8];
    v[0] = y0.x + __uint_as_float(q.x << 16);
    v[1] = y0.y + __uint_as_float(q.x & 0xffff0000u);
    v[2] = y0.z + __uint_as_float(q.y << 16);
    v[3] = y0.w + __uint_as_float(q.y & 0xffff0000u);
    v[4] = y1.x + __uint_as_float(q.z << 16);
    v[5] = y1.y + __uint_as_float(q.z & 0xffff0000u);
    v[6] = y1.z + __uint_as_float(q.w << 16);
    v[7] = y1.w + __uint_as_float(q.w & 0xffff0000u);
    float s = 0.f, sq = 0.f;
    #pragma unroll
    for (int j = 0; j < 8; ++j) { s += v[j]; sq += v[j] * v[j]; }
    #pragma unroll
    for (int o = 32; o > 0; o >>= 1) { s += __shfl_down(s, o); sq += __shfl_down(sq, o); }
    s = __shfl(s, 0); sq = __shfl(sq, 0);
    float mean = s * (1.0f / 512.0f);
    float var = sq * (1.0f / 512.0f) - mean * mean;
    float rstd = rsqrtf(var + 1e-5f);
    float4 g0 = *reinterpret_cast<const float4*>(g3 + kb);
    float4 g1 = *reinterpret_cast<const float4*>(g3 + kb + 4);
    float4 b0 = *reinterpret_cast<const float4*>(be3 + kb);
    float4 b1 = *reinterpret_cast<const float4*>(be3 + kb + 4);
    float gv[8] = {g0.x, g0.y, g0.z, g0.w, g1.x, g1.y, g1.z, g1.w};
    float bv[8] = {b0.x, b0.y, b0.z, b0.w, b1.x, b1.y, b1.z, b1.w};
    #pragma unroll
    for (int j = 0; j < 8; ++j)
      ynorm[l][kb + j] = (v[j] - mean) * rstd * gv[j] + bv[j];
  }
  __syncthreads();
  float* ob = out + (size_t)blockIdx.x * 4096;
  #pragma unroll
  for (int kk = 0; kk < 2; ++kk) {
    int k = tid * 2 + kk;
    float4 lo = make_float4(ynorm[0][k], ynorm[1][k], ynorm[2][k], ynorm[3][k]);
    float4 hi = make_float4(ynorm[4][k], ynorm[5][k], ynorm[6][k], ynorm[7][k]);
    *reinterpret_cast<float4*>(ob + (size_t)k * 8)     = lo;
    *reinterpret_cast<float4*>(ob + (size_t)k * 8 + 4) = hi;
  }
}

// ================= slow-path fp32 kernels (fallback only) =================
#define TS 64
#define KT 16
__global__ __launch_bounds__(256) void k_build_x_s(const float* __restrict__ lags,
                                                   float* __restrict__ x, int b_base) {
  int idx = blockIdx.x * 256 + threadIdx.x;
  int k = idx & (D_ - 1);
  int r = idx >> 9;
  int b = b_base + r / SQ;
  int t = r - (r / SQ) * SQ;
  int si = t >> 3, l = t & 7;
  size_t src = (((size_t)(b * S_ + si) * D_ + k) << 3) + l;
  x[idx] = lags[src];
}

__global__ __launch_bounds__(256) void k_scores(const float* __restrict__ x,
                                                float* __restrict__ sc, int b_base) {
  const float* A = x;
  float* C = sc;
  __shared__ float As[TS][KT + 1];
  __shared__ float Bs[TS][KT + 1];
  int tx = threadIdx.x & 15, ty = threadIdx.x >> 4;
  int j0 = blockIdx.x * TS, i0 = blockIdx.y * TS;
  float acc[4][4] = {};
  int lk = threadIdx.x & 15, lr = threadIdx.x >> 4;
  for (int k0 = 0; k0 < D_; k0 += KT) {
    #pragma unroll
    for (int it = 0; it < 4; ++it) {
      As[lr + 16 * it][lk] = A[(size_t)(i0 + lr + 16 * it) * D_ + k0 + lk];
      Bs[lr + 16 * it][lk] = A[(size_t)(j0 + lr + 16 * it) * D_ + k0 + lk];
    }
    __syncthreads();
    #pragma unroll
    for (int kk = 0; kk < KT; ++kk) {
      float a[4], bb[4];
      #pragma unroll
      for (int r = 0; r < 4; ++r) a[r] = As[ty * 4 + r][kk];
      #pragma unroll
      for (int c = 0; c < 4; ++c) bb[c] = Bs[tx * 4 + c][kk];
      #pragma unroll
      for (int r = 0; r < 4; ++r)
        #pragma unroll
        for (int c = 0; c < 4; ++c) acc[r][c] = fmaf(a[r], bb[c], acc[r][c]);
    }
    __syncthreads();
  }
  #pragma unroll
  for (int r = 0; r < 4; ++r) {
    float4 v = make_float4(acc[r][0]*SCALE_QK, acc[r][1]*SCALE_QK,
                           acc[r][2]*SCALE_QK, acc[r][3]*SCALE_QK);
    *reinterpret_cast<float4*>(&C[(size_t)(i0 + ty*4 + r) * SQ + j0 + tx*4]) = v;
  }
}

__global__ __launch_bounds__(256) void k_softmax(float* __restrict__ sc) {
  float* row = sc + (size_t)blockIdx.x * SQ;
  int tid = threadIdx.x;
  __shared__ float red[8];
  float m = -1e30f;
  for (int j = tid; j < SQ; j += 256) m = fmaxf(m, row[j]);
  #pragma unroll
  for (int o = 32; o > 0; o >>= 1) m = fmaxf(m, __shfl_down(m, o));
  if ((tid & 63) == 0) red[tid >> 6] = m;
  __syncthreads();
  m = fmaxf(fmaxf(red[0], red[1]), fmaxf(red[2], red[3]));
  __syncthreads();
  float ssum = 0.f;
  for (int j = tid; j < SQ; j += 256) { float e = expf(row[j] - m); row[j] = e; ssum += e; }
  #pragma unroll
  for (int o = 32; o > 0; o >>= 1) ssum += __shfl_down(ssum, o);
  if ((tid & 63) == 0) red[4 + (tid >> 6)] = ssum;
  __syncthreads();
  float inv = 1.0f / (red[4] + red[5] + red[6] + red[7]);
  for (int j = tid; j < SQ; j += 256) row[j] *= inv;
}

__global__ __launch_bounds__(256) void k_attn(const float* __restrict__ x,
                                              const float* __restrict__ sc,
                                              float* __restrict__ attn) {
  const float* X = x;
  const float* P = sc;
  float* O = attn;
  __shared__ float Ps[TS][KT + 1];
  __shared__ float Xs[KT][TS];
  int tx = threadIdx.x & 15, ty = threadIdx.x >> 4;
  int j0 = blockIdx.x * TS, i0 = blockIdx.y * TS;
  float acc[4][4] = {};
  int lk = threadIdx.x & 15, lr = threadIdx.x >> 4;
  int lc = threadIdx.x & 63, lrow = threadIdx.x >> 6;
  for (int k0 = 0; k0 < SQ; k0 += KT) {
    #pragma unroll
    for (int it = 0; it < 4; ++it)
      Ps[lr + 16 * it][lk] = P[(size_t)(i0 + lr + 16 * it) * SQ + k0 + lk];
    #pragma unroll
    for (int it = 0; it < 4; ++it)
      Xs[lrow + 4 * it][lc] = X[(size_t)(k0 + lrow + 4 * it) * D_ + j0 + lc];
    __syncthreads();
    #pragma unroll
    for (int kk = 0; kk < KT; ++kk) {
      float a[4], bb[4];
      #pragma unroll
      for (int r = 0; r < 4; ++r) a[r] = Ps[ty * 4 + r][kk];
      #pragma unroll
      for (int c = 0; c < 4; ++c) bb[c] = Xs[kk][tx * 4 + c];
      #pragma unroll
      for (int r = 0; r < 4; ++r)
        #pragma unroll
        for (int c = 0; c < 4; ++c) acc[r][c] = fmaf(a[r], bb[c], acc[r][c]);
    }
    __syncthreads();
  }
  #pragma unroll
  for (int r = 0; r < 4; ++r) {
    float4 v = make_float4(acc[r][0], acc[r][1], acc[r][2], acc[r][3]);
    *reinterpret_cast<float4*>(&O[(size_t)(i0 + ty*4 + r) * D_ + j0 + tx*4]) = v;
  }
}

__global__ __launch_bounds__(256) void k_ln1(const float* __restrict__ x,
                                             const float* __restrict__ attn,
                                             const float* __restrict__ g,
                                             const float* __restrict__ be,
                                             float* __restrict__ qout) {
  size_t base = (size_t)blockIdx.x * D_;
  int tid = threadIdx.x;
  __shared__ float rl[8];
  float v0 = x[base + tid] + attn[base + tid];
  float v1 = x[base + tid + 256] + attn[base + tid + 256];
  float s = v0 + v1, sq = v0 * v0 + v1 * v1;
  #pragma unroll
  for (int o = 32; o > 0; o >>= 1) { s += __shfl_down(s, o); sq += __shfl_down(sq, o); }
  int lane = tid & 63, wid = tid >> 6;
  if (lane == 0) { rl[wid] = s; rl[4 + wid] = sq; }
  __syncthreads();
  s = rl[0] + rl[1] + rl[2] + rl[3];
  sq = rl[4] + rl[5] + rl[6] + rl[7];
  float mean = s * (1.0f / 512.0f);
  float var = sq * (1.0f / 512.0f) - mean * mean;
  float rstd = rsqrtf(var + 1e-5f);
  qout[base + tid]       = (v0 - mean) * rstd * g[tid] + be[tid];
  qout[base + tid + 256] = (v1 - mean) * rstd * g[tid + 256] + be[tid + 256];
}

__global__ __launch_bounds__(256, 2) void k_ffn(
    const float* __restrict__ q,
    const float* __restrict__ W1, const float* __restrict__ b1,
    const float* __restrict__ W2, const float* __restrict__ b2,
    const float* __restrict__ g3, const float* __restrict__ be3,
    float* __restrict__ out, int row_base)
{
  __shared__ float qs[8][D_];
  __shared__ float mid[8][H_];
  const int tid = threadIdx.x;
  const int row0 = blockIdx.x * 8;
  for (int idx = tid; idx < 8 * D_; idx += 256)
    qs[idx >> 9][idx & (D_ - 1)] = q[(size_t)row0 * D_ + idx];
  __syncthreads();
  float acc[8][8];
  {
    float4 bA = *reinterpret_cast<const float4*>(b1 + (tid << 3));
    float4 bB = *reinterpret_cast<const float4*>(b1 + (tid << 3) + 4);
    float bv[8] = {bA.x, bA.y, bA.z, bA.w, bB.x, bB.y, bB.z, bB.w};
    #pragma unroll
    for (int jj = 0; jj < 8; ++jj)
      #pragma unroll
      for (int r = 0; r < 8; ++r) acc[jj][r] = bv[jj];
  }
  for (int k4 = 0; k4 < D_ / 4; ++k4) {
    float4 qv[8];
    #pragma unroll
    for (int r = 0; r < 8; ++r)
      qv[r] = *reinterpret_cast<const float4*>(&qs[r][k4 << 2]);
    #pragma unroll
    for (int kk = 0; kk < 4; ++kk) {
      const int k = (k4 << 2) + kk;
      float4 wA = *reinterpret_cast<const float4*>(W1 + (size_t)k * H_ + (tid << 3));
      float4 wB = *reinterpret_cast<const float4*>(W1 + (size_t)k * H_ + (tid << 3) + 4);
      float wv[8] = {wA.x, wA.y, wA.z, wA.w, wB.x, wB.y, wB.z, wB.w};
      #pragma unroll
      for (int r = 0; r < 8; ++r) {
        float qk = (kk == 0) ? qv[r].x : (kk == 1) ? qv[r].y : (kk == 2) ? qv[r].z : qv[r].w;
        #pragma unroll
        for (int jj = 0; jj < 8; ++jj) acc[jj][r] = fmaf(qk, wv[jj], acc[jj][r]);
      }
    }
  }
  #pragma unroll
  for (int jj = 0; jj < 8; ++jj)
    #pragma unroll
    for (int r = 0; r < 8; ++r) {
      float v = acc[jj][r];
      mid[r][(tid << 3) + jj] = 0.5f * v * (1.0f + erff(v * 0.70710678118654752f));
    }
  __syncthreads();
  float acc2[8][2];
  {
    float b20 = b2[tid << 1], b21 = b2[(tid << 1) + 1];
    #pragma unroll
    for (int r = 0; r < 8; ++r) { acc2[r][0] = b20; acc2[r][1] = b21; }
  }
  for (int j4 = 0; j4 < H_ / 4; ++j4) {
    float4 mv[8];
    #pragma unroll
    for (int r = 0; r < 8; ++r)
      mv[r] = *reinterpret_cast<const float4*>(&mid[r][j4 << 2]);
    #pragma unroll
    for (int kk = 0; kk < 4; ++kk) {
      const int j = (j4 << 2) + kk;
      float2 wv = *reinterpret_cast<const float2*>(W2 + (size_t)j * D_ + (tid << 1));
      #pragma unroll
      for (int r = 0; r < 8; ++r) {
        float m = (kk == 0) ? mv[r].x : (kk == 1) ? mv[r].y : (kk == 2) ? mv[r].z : mv[r].w;
        acc2[r][0] = fmaf(m, wv.x, acc2[r][0]);
        acc2[r][1] = fmaf(m, wv.y, acc2[r][1]);
      }
    }
  }
  __syncthreads();
  float* ys = &mid[0][0];
  #pragma unroll
  for (int r = 0; r < 8; ++r) {
    ys[r * D_ + (tid << 1)]     = qs[r][(tid << 1)]     + acc2[r][0];
    ys[r * D_ + (tid << 1) + 1] = qs[r][(tid << 1) + 1] + acc2[r][1];
  }
  __syncthreads();
  float g3a = g3[tid],  g3b = g3[tid + 256];
  float be3a = be3[tid], be3b = be3[tid + 256];
  float* rl = &qs[0][0];
  for (int r = 0; r < 8; ++r) {
    float v0 = ys[r * D_ + tid], v1 = ys[r * D_ + tid + 256];
    float s = v0 + v1, sq = v0 * v0 + v1 * v1;
    #pragma unroll
    for (int o = 32; o > 0; o >>= 1) { s += __shfl_down(s, o); sq += __shfl_down(sq, o); }
    int lane = tid & 63, wid = tid >> 6;
    if (lane == 0) { rl[wid] = s; rl[4 + wid] = sq; }
    __syncthreads();
    s = rl[0] + rl[1] + rl[2] + rl[3];
    sq = rl[4] + rl[5] + rl[6] + rl[7];
    __syncthreads();
    float mean = s * (1.0f / 512.0f);
    float var = sq * (1.0f / 512.0f) - mean * mean;
    float rstd = rsqrtf(var + 1e-5f);
    int t = row_base + row0 + r;
    int b = t / SQ, tt = t - b * SQ;
    int si = tt >> 3, l = tt & 7;
    size_t ob = (((size_t)(b * S_ + si) * D_) << 3) + l;
    out[ob + ((size_t)tid << 3)]         = (v0 - mean) * rstd * g3a + be3a;
    out[ob + ((size_t)(tid + 256) << 3)] = (v1 - mean) * rstd * g3b + be3b;
  }
}

extern "C" void kernel_launch(void* const* d_in, const int* in_sizes, int n_in,
                              void* d_out, int out_size, void* d_ws, size_t ws_size,
                              hipStream_t stream) {
  const float* lags   = (const float*)d_in[0];
  const float* gamma1 = (const float*)d_in[1];
  const float* beta1  = (const float*)d_in[2];
  const float* W1     = (const float*)d_in[3];
  const float* b1     = (const float*)d_in[4];
  const float* W2     = (const float*)d_in[5];
  const float* b2     = (const float*)d_in[6];
  const float* g3     = (const float*)d_in[7];
  const float* be3    = (const float*)d_in[8];
  float* out = (float*)d_out;

  float* ws = (float*)d_ws;
  const size_t NX  = (size_t)B_ * SQ * D_;   // 6,291,456
  const size_t NXB = (size_t)SQ * D_;        //   786,432
  const size_t NS  = (size_t)SQ * SQ;        // 2,359,296

  const size_t need_full = (3 * NX + 8 * NS) * sizeof(float);  // ~151 MB (proven available)

  if (ws_size >= need_full) {
    // ---- fast path layout (~130 MB) ----
    float* x        = ws;                                   // NX f32
    float* attn     = x + NX;                               // NX f32 (later: y)
    ushort_t* q_bf  = (ushort_t*)(attn + NX);               // NX us
    ushort_t* w1t   = q_bf + NX;                            // H*D us
    ushort_t* w2t   = w1t + (size_t)H_ * D_;                // H*D us
    float* rowsum   = (float*)(w2t + (size_t)H_ * D_);      // B*SQ f32 (48 KB)
    ushort_t* region = (ushort_t*)(rowsum + (size_t)B_ * SQ); // 8*NS + 2*NX us
    ushort_t* sc_bf = region;                               // exp-scores, bf16
    ushort_t* x_bf  = region + 8 * NS;
    ushort_t* xT_bf = x_bf + NX;
    ushort_t* mid_bf = region;                              // aliases dead sc/x_bf/xT_bf

    // build x/x_bf/xT + zero rowsum + cast/transpose W1,W2 (one dispatch)
    k_prep<<<dim3(2048), 256, 0, stream>>>(lags, x, x_bf, xT_bf, rowsum,
                                           W1, w1t, W2, w2t);
    // P = exp(scale * X X^T) -> bf16 (SYMMETRIC: 78 triangular blocks/batch,
    // off-diagonal tiles mirrored via LDS transpose, coalesced write-out);
    // rowsum accumulated (row + column sums). No max-sub needed: scores <= ~31.
    k_gemm<6><<<dim3(78, 1, B_), 256, 0, stream>>>(
        x_bf, x_bf, nullptr, rowsum, sc_bf, SQ, D_, SQ, NXB, NXB, NS, SCALE_QK2);
    // attn = (P @ X) / rowsum -> f32  (softmax normalization folded in)
    k_gemm<5><<<dim3(D_ / 128, SQ / 128, B_), 256, 0, stream>>>(
        sc_bf, xT_bf, nullptr, rowsum, attn, SQ, SQ, D_, NS, NXB, NXB, 1.0f);
    k_ln1b<<<dim3(NROW / 4), 256, 0, stream>>>(x, attn, gamma1, beta1, q_bf);
    // mid = gelu(q @ W1 + b1) -> bf16
    k_gemm<0><<<dim3(H_ / 128, NROW / 128, 1), 256, 0, stream>>>(
        q_bf, w1t, b1, nullptr, mid_bf, NROW, D_, H_, 0, 0, 0, 1.0f);
    // y = mid @ W2 + b2 -> f32 (attn buffer)
    k_gemm<1><<<dim3(D_ / 128, NROW / 128, 1), 256, 0, stream>>>(
        mid_bf, w2t, b2, nullptr, attn, NROW, H_, D_, 0, 0, 0, 1.0f);
    k_ln3_f<<<dim3(B_ * S_), 256, 0, stream>>>(attn, q_bf, g3, be3, out);
  } else {
    // ---- minimal-footprint fallback (fp32, per-batch) ----
    float* xb   = ws;
    float* sc   = xb + NXB;
    float* atb  = sc + NS;
    float* qb   = atb + NXB;
    for (int b = 0; b < B_; ++b) {
      k_build_x_s<<<dim3((unsigned)(NXB / 256)), 256, 0, stream>>>(lags, xb, b);
      k_scores<<<dim3(SQ / TS, SQ / TS, 1), 256, 0, stream>>>(xb, sc, b);
      k_softmax<<<dim3(SQ, 1, 1), 256, 0, stream>>>(sc);
      k_attn<<<dim3(D_ / TS, SQ / TS, 1), 256, 0, stream>>>(xb, sc, atb);
      k_ln1<<<dim3(SQ), 256, 0, stream>>>(xb, atb, gamma1, beta1, qb);
      k_ffn<<<dim3(SQ / 8), 256, 0, stream>>>(qb, W1, b1, W2, b2, g3, be3, out, b * SQ);
    }
  }
}